// Round 1
// baseline (3400.029 us; speedup 1.0000x reference)
//
#include <hip/hip_runtime.h>

#define NN   100000
#define NE   500000
#define DD   128
#define HH   4
#define CC   32
#define HIDD 512
#define EPSF 1e-5f

// ---- order-preserving float<->uint encode for atomicMax on floats ----
__device__ __forceinline__ unsigned f2o(float f) {
  unsigned u = __float_as_uint(f);
  return (u & 0x80000000u) ? ~u : (u | 0x80000000u);
}
__device__ __forceinline__ float o2f(unsigned u) {
  return (u & 0x80000000u) ? __uint_as_float(u ^ 0x80000000u) : __uint_as_float(~u);
}

__global__ void k_init(unsigned* __restrict__ m, float* __restrict__ z) {
  int i = blockIdx.x * 256 + threadIdx.x;
  if (i < NN * HH) { m[i] = 0u; z[i] = 0.f; }
}

__device__ __forceinline__ void dot44(float acc[4][4], const float4 a[4], const float4 w[4]) {
#pragma unroll
  for (int i = 0; i < 4; i++)
#pragma unroll
    for (int j = 0; j < 4; j++)
      acc[i][j] += a[i].x * w[j].x + a[i].y * w[j].y + a[i].z * w[j].z + a[i].w * w[j].w;
}

// Y[n,o] = sum_k X[n,k] * W[o,k] + B[o]   (32-row tile, all 128 cols per block)
__global__ __launch_bounds__(256) void k_gemm128(const float* __restrict__ X,
                                                 const float* __restrict__ W,
                                                 const float* __restrict__ B,
                                                 float* __restrict__ Y) {
  __shared__ float As[32][DD];
  const int t = threadIdx.x;
  const size_t n0 = (size_t)blockIdx.x * 32;
  {
    const float4* src = (const float4*)(X + n0 * DD);
    float4* dst = (float4*)&As[0][0];
#pragma unroll
    for (int i = 0; i < 4; i++) dst[t + 256 * i] = src[t + 256 * i];
  }
  __syncthreads();
  const int r0 = (t >> 5) * 4, o0 = (t & 31) * 4;
  float acc[4][4] = {};
  for (int k0 = 0; k0 < DD; k0 += 4) {
    float4 a[4], w[4];
#pragma unroll
    for (int i = 0; i < 4; i++) a[i] = *(const float4*)&As[r0 + i][k0];
#pragma unroll
    for (int j = 0; j < 4; j++) w[j] = *(const float4*)&W[(size_t)(o0 + j) * DD + k0];
    dot44(acc, a, w);
  }
#pragma unroll
  for (int i = 0; i < 4; i++) {
    float4 o;
    o.x = acc[i][0] + B[o0 + 0];
    o.y = acc[i][1] + B[o0 + 1];
    o.z = acc[i][2] + B[o0 + 2];
    o.w = acc[i][3] + B[o0 + 3];
    *(float4*)&Y[(n0 + r0 + i) * DD + o0] = o;
  }
}

// per-(edge,head) attention logit + segment max via encoded atomicMax
__global__ void k_alpha(const int* __restrict__ ei, const float* __restrict__ q,
                        const float* __restrict__ kk, float* __restrict__ alpha,
                        unsigned* __restrict__ m) {
  int tid = blockIdx.x * 256 + threadIdx.x;
  if (tid >= NE * HH) return;
  int e = tid >> 2, h = tid & 3;
  int s = ei[e], d = ei[NE + e];
  const float4* qa = (const float4*)(q + (size_t)d * DD + h * CC);
  const float4* ka = (const float4*)(kk + (size_t)s * DD + h * CC);
  float acc = 0.f;
#pragma unroll
  for (int i = 0; i < 8; i++) {
    float4 a = qa[i], b = ka[i];
    acc += a.x * b.x + a.y * b.y + a.z * b.z + a.w * b.w;
  }
  acc *= 0.17677669529663687f;  // 1/sqrt(32)
  alpha[tid] = acc;
  atomicMax(m + (size_t)d * HH + h, f2o(acc));
}

// e = exp(alpha - m[dst]); z[dst] += e (overwrites alpha with e)
__global__ void k_expz(const int* __restrict__ ei, float* __restrict__ alpha,
                       const unsigned* __restrict__ m, float* __restrict__ z) {
  int tid = blockIdx.x * 256 + threadIdx.x;
  if (tid >= NE * HH) return;
  int e = tid >> 2, h = tid & 3;
  int d = ei[NE + e];
  float mm = o2f(m[(size_t)d * HH + h]);
  float ex = __expf(alpha[tid] - mm);
  alpha[tid] = ex;
  atomicAdd(z + (size_t)d * HH + h, ex);
}

// conv[dst, c] += (e/z[dst]) * v[src, c]   (32 threads per edge, float4 channels)
__global__ void k_aggr(const int* __restrict__ ei, const float* __restrict__ alpha,
                       const float* __restrict__ z, const float* __restrict__ v,
                       float* __restrict__ conv) {
  int tid = blockIdx.x * 256 + threadIdx.x;  // grid sized exactly NE*32
  int e = tid >> 5, lt = tid & 31;
  int c0 = lt * 4, h = lt >> 3;
  int s = ei[e], d = ei[NE + e];
  float a = alpha[(size_t)e * HH + h] / z[(size_t)d * HH + h];
  float4 vv = *(const float4*)&v[(size_t)s * DD + c0];
  float* dst = conv + (size_t)d * DD + c0;
  atomicAdd(dst + 0, a * vv.x);
  atomicAdd(dst + 1, a * vv.y);
  atomicAdd(dst + 2, a * vv.z);
  atomicAdd(dst + 3, a * vv.w);
}

// shared LN epilogue: row sums across the 32-lane half-wave holding one row
__device__ __forceinline__ void ln_write(float val[4][4], const float* __restrict__ lw,
                                         const float* __restrict__ lb, float* __restrict__ out,
                                         size_t n0, int r0, int o0) {
#pragma unroll
  for (int i = 0; i < 4; i++) {
    float s = val[i][0] + val[i][1] + val[i][2] + val[i][3];
#pragma unroll
    for (int msk = 16; msk >= 1; msk >>= 1) s += __shfl_xor(s, msk, 64);
    const float mu = s * (1.f / 128.f);
    float d0 = val[i][0] - mu, d1 = val[i][1] - mu, d2 = val[i][2] - mu, d3 = val[i][3] - mu;
    float vs = d0 * d0 + d1 * d1 + d2 * d2 + d3 * d3;
#pragma unroll
    for (int msk = 16; msk >= 1; msk >>= 1) vs += __shfl_xor(vs, msk, 64);
    const float rs = rsqrtf(vs * (1.f / 128.f) + EPSF);
    float4 o;
    o.x = d0 * rs * lw[o0 + 0] + lb[o0 + 0];
    o.y = d1 * rs * lw[o0 + 1] + lb[o0 + 1];
    o.z = d2 * rs * lw[o0 + 2] + lb[o0 + 2];
    o.w = d3 * rs * lw[o0 + 3] + lb[o0 + 3];
    *(float4*)&out[(n0 + r0 + i) * DD + o0] = o;
  }
}

// out2 = LN(conv @ Wout^T + bout + x) * lw + lb
__global__ __launch_bounds__(256) void k_out1ln(const float* __restrict__ conv,
                                                const float* __restrict__ W,
                                                const float* __restrict__ B,
                                                const float* __restrict__ x,
                                                const float* __restrict__ lw,
                                                const float* __restrict__ lb,
                                                float* __restrict__ out2) {
  __shared__ float As[32][DD];
  const int t = threadIdx.x;
  const size_t n0 = (size_t)blockIdx.x * 32;
  {
    const float4* src = (const float4*)(conv + n0 * DD);
    float4* dst = (float4*)&As[0][0];
#pragma unroll
    for (int i = 0; i < 4; i++) dst[t + 256 * i] = src[t + 256 * i];
  }
  __syncthreads();
  const int r0 = (t >> 5) * 4, o0 = (t & 31) * 4;
  float acc[4][4] = {};
  for (int k0 = 0; k0 < DD; k0 += 4) {
    float4 a[4], w[4];
#pragma unroll
    for (int i = 0; i < 4; i++) a[i] = *(const float4*)&As[r0 + i][k0];
#pragma unroll
    for (int j = 0; j < 4; j++) w[j] = *(const float4*)&W[(size_t)(o0 + j) * DD + k0];
    dot44(acc, a, w);
  }
  float val[4][4];
#pragma unroll
  for (int i = 0; i < 4; i++) {
    const float4 xr = *(const float4*)&x[(n0 + r0 + i) * DD + o0];
    val[i][0] = acc[i][0] + B[o0 + 0] + xr.x;
    val[i][1] = acc[i][1] + B[o0 + 1] + xr.y;
    val[i][2] = acc[i][2] + B[o0 + 2] + xr.z;
    val[i][3] = acc[i][3] + B[o0 + 3] + xr.w;
  }
  ln_write(val, lw, lb, out2, n0, r0, o0);
}

// out = LN(relu(out2@W1^T+b1)@W2^T + b2 + out2) * lw + lb   (hidden tile in LDS)
__global__ __launch_bounds__(256) void k_ffn(const float* __restrict__ out2,
                                             const float* __restrict__ W1,
                                             const float* __restrict__ B1,
                                             const float* __restrict__ W2,
                                             const float* __restrict__ B2,
                                             const float* __restrict__ lw,
                                             const float* __restrict__ lb,
                                             float* __restrict__ out) {
  __shared__ float As[32][DD];     // 16 KB: out2 tile (also residual)
  __shared__ float Hs[32][HIDD];   // 64 KB: hidden tile
  const int t = threadIdx.x;
  const size_t n0 = (size_t)blockIdx.x * 32;
  {
    const float4* src = (const float4*)(out2 + n0 * DD);
    float4* dst = (float4*)&As[0][0];
#pragma unroll
    for (int i = 0; i < 4; i++) dst[t + 256 * i] = src[t + 256 * i];
  }
  __syncthreads();
  const int r0 = (t >> 5) * 4, q0 = (t & 31) * 4;
  // phase 1: Hs = relu(As @ W1^T + b1)
#pragma unroll
  for (int jt = 0; jt < 4; jt++) {
    const int j0 = q0 + jt * 128;
    float acc[4][4] = {};
    for (int k0 = 0; k0 < DD; k0 += 4) {
      float4 a[4], w[4];
#pragma unroll
      for (int i = 0; i < 4; i++) a[i] = *(const float4*)&As[r0 + i][k0];
#pragma unroll
      for (int j = 0; j < 4; j++) w[j] = *(const float4*)&W1[(size_t)(j0 + j) * DD + k0];
      dot44(acc, a, w);
    }
#pragma unroll
    for (int i = 0; i < 4; i++) {
      float4 hv;
      hv.x = fmaxf(acc[i][0] + B1[j0 + 0], 0.f);
      hv.y = fmaxf(acc[i][1] + B1[j0 + 1], 0.f);
      hv.z = fmaxf(acc[i][2] + B1[j0 + 2], 0.f);
      hv.w = fmaxf(acc[i][3] + B1[j0 + 3], 0.f);
      *(float4*)&Hs[r0 + i][j0] = hv;
    }
  }
  __syncthreads();
  // phase 2: out3 = Hs @ W2^T + b2 ; then +out2 residual, LN
  float acc[4][4] = {};
  for (int j0 = 0; j0 < HIDD; j0 += 4) {
    float4 h[4], w[4];
#pragma unroll
    for (int i = 0; i < 4; i++) h[i] = *(const float4*)&Hs[r0 + i][j0];
#pragma unroll
    for (int j = 0; j < 4; j++) w[j] = *(const float4*)&W2[(size_t)(q0 + j) * HIDD + j0];
    dot44(acc, h, w);
  }
  float val[4][4];
#pragma unroll
  for (int i = 0; i < 4; i++) {
#pragma unroll
    for (int j = 0; j < 4; j++)
      val[i][j] = acc[i][j] + B2[q0 + j] + As[r0 + i][q0 + j];
  }
  ln_write(val, lw, lb, out, n0, r0, q0);
}

extern "C" void kernel_launch(void* const* d_in, const int* in_sizes, int n_in,
                              void* d_out, int out_size, void* d_ws, size_t ws_size,
                              hipStream_t stream) {
  const float* x   = (const float*)d_in[0];
  const int*   ei  = (const int*)d_in[1];
  const float* Wq  = (const float*)d_in[2];
  const float* bq  = (const float*)d_in[3];
  const float* Wk  = (const float*)d_in[4];
  const float* bk  = (const float*)d_in[5];
  const float* Wv  = (const float*)d_in[6];
  const float* bv  = (const float*)d_in[7];
  const float* Wsk = (const float*)d_in[8];
  const float* bsk = (const float*)d_in[9];
  const float* Wo  = (const float*)d_in[10];
  const float* bo  = (const float*)d_in[11];
  const float* l1w = (const float*)d_in[12];
  const float* l1b = (const float*)d_in[13];
  const float* l2w = (const float*)d_in[14];
  const float* l2b = (const float*)d_in[15];
  const float* W1  = (const float*)d_in[16];
  const float* b1  = (const float*)d_in[17];
  const float* W2  = (const float*)d_in[18];
  const float* b2  = (const float*)d_in[19];

  float* ws    = (float*)d_ws;
  float* q     = ws;
  float* kbuf  = q + (size_t)NN * DD;
  float* v     = kbuf + (size_t)NN * DD;
  float* conv  = v + (size_t)NN * DD;
  float* out2  = conv + (size_t)NN * DD;
  float* alpha = out2 + (size_t)NN * DD;
  unsigned* m  = (unsigned*)(alpha + (size_t)NE * HH);
  float* z     = (float*)(m + (size_t)NN * HH);
  float* outf  = (float*)d_out;

  k_init<<<dim3((NN * HH + 255) / 256), dim3(256), 0, stream>>>(m, z);
  k_gemm128<<<dim3(NN / 32), dim3(256), 0, stream>>>(x, Wq, bq, q);
  k_gemm128<<<dim3(NN / 32), dim3(256), 0, stream>>>(x, Wk, bk, kbuf);
  k_gemm128<<<dim3(NN / 32), dim3(256), 0, stream>>>(x, Wv, bv, v);
  k_gemm128<<<dim3(NN / 32), dim3(256), 0, stream>>>(x, Wsk, bsk, conv);  // conv starts as skip
  k_alpha<<<dim3((NE * HH + 255) / 256), dim3(256), 0, stream>>>(ei, q, kbuf, alpha, m);
  k_expz<<<dim3((NE * HH + 255) / 256), dim3(256), 0, stream>>>(ei, alpha, m, z);
  k_aggr<<<dim3(NE * 32 / 256), dim3(256), 0, stream>>>(ei, alpha, z, v, conv);
  k_out1ln<<<dim3(NN / 32), dim3(256), 0, stream>>>(conv, Wo, bo, x, l1w, l1b, out2);
  k_ffn<<<dim3(NN / 32), dim3(256), 0, stream>>>(out2, W1, b1, W2, b2, l2w, l2b, outf);
}

// Round 3
// 1312.811 us; speedup vs baseline: 2.5899x; 2.5899x over previous
//
#include <hip/hip_runtime.h>

#define NN   100000
#define NE   500000
#define DD   128
#define HH   4
#define CC   32
#define HIDD 512
#define EPSF 1e-5f

typedef __bf16 bf16x8 __attribute__((ext_vector_type(8)));
typedef float  f32x4  __attribute__((ext_vector_type(4)));

__device__ __forceinline__ unsigned short f2b(float f) {
  unsigned u = __float_as_uint(f);
  unsigned r = (u + 0x7FFFu + ((u >> 16) & 1)) >> 16;
  return (unsigned short)r;
}

// ---- order-preserving float<->uint encode for atomicMax on floats ----
__device__ __forceinline__ unsigned f2o(float f) {
  unsigned u = __float_as_uint(f);
  return (u & 0x80000000u) ? ~u : (u | 0x80000000u);
}
__device__ __forceinline__ float o2f(unsigned u) {
  return (u & 0x80000000u) ? __uint_as_float(u ^ 0x80000000u) : __uint_as_float(~u);
}

__global__ void k_init(unsigned* __restrict__ m, float* __restrict__ z) {
  int i = blockIdx.x * 256 + threadIdx.x;
  if (i < NN * HH) { m[i] = 0u; z[i] = 0.f; }
}

// fp32 -> bf16 cast, 4 elems/thread
__global__ void k_cast(const float* __restrict__ src, unsigned short* __restrict__ dst, int n) {
  int i = (blockIdx.x * 256 + threadIdx.x) * 4;
  if (i >= n) return;
  float4 v = *(const float4*)&src[i];
  ushort4 o;
  o.x = f2b(v.x); o.y = f2b(v.y); o.z = f2b(v.z); o.w = f2b(v.w);
  *(ushort4*)&dst[i] = o;
}

// ---------------- MFMA GEMM: out[n, col0+0..127] = A[n,:K] @ W[col,:K]^T + bias ----------------
// A: bf16 [N, KTOT] row-major; W: bf16 [O_total, KTOT] row-major.
// 128x128 tile per block, 4 waves each 32 rows x 128 cols.
template <int KTOT, bool RELU, bool WF32, bool WB16>
__global__ __launch_bounds__(256) void k_mfma_gemm(const unsigned short* __restrict__ A,
                                                   const unsigned short* __restrict__ W,
                                                   const float* __restrict__ bias,
                                                   float* __restrict__ outF,
                                                   unsigned short* __restrict__ outB,
                                                   int ldo) {
  __shared__ unsigned short As[128 * 128];
  __shared__ unsigned short Ws[128 * 128];
  const int t = threadIdx.x;
  const int n0 = blockIdx.x * 128;
  const int col0 = blockIdx.y * 128;
  const int w = t >> 6, l = t & 63;

  f32x4 acc[2][8] = {};

  for (int kc = 0; kc < KTOT / 128; ++kc) {
    __syncthreads();
    // stage A tile (row-swizzled 16B slots: slot ^= row&7)
#pragma unroll
    for (int i = 0; i < 8; i++) {
      int chunk = t + i * 256;          // 0..2047
      int row = chunk >> 4, c16 = chunk & 15;
      uint4 val = make_uint4(0u, 0u, 0u, 0u);
      int gr = n0 + row;
      if (gr < NN) val = *(const uint4*)(A + (size_t)gr * KTOT + kc * 128 + c16 * 8);
      *(uint4*)&As[row * 128 + ((c16 ^ (row & 7)) * 8)] = val;
    }
    // stage W tile
#pragma unroll
    for (int i = 0; i < 8; i++) {
      int chunk = t + i * 256;
      int row = chunk >> 4, c16 = chunk & 15;
      uint4 val = *(const uint4*)(W + (size_t)(col0 + row) * KTOT + kc * 128 + c16 * 8);
      *(uint4*)&Ws[row * 128 + ((c16 ^ (row & 7)) * 8)] = val;
    }
    __syncthreads();
#pragma unroll
    for (int ks = 0; ks < 4; ks++) {
      bf16x8 a[2], b[8];
      const int c16 = ks * 4 + (l >> 4);
#pragma unroll
      for (int rt = 0; rt < 2; rt++) {
        int row = w * 32 + rt * 16 + (l & 15);
        a[rt] = *(const bf16x8*)&As[row * 128 + ((c16 ^ (row & 7)) * 8)];
      }
#pragma unroll
      for (int ct = 0; ct < 8; ct++) {
        int row = ct * 16 + (l & 15);
        b[ct] = *(const bf16x8*)&Ws[row * 128 + ((c16 ^ (row & 7)) * 8)];
      }
#pragma unroll
      for (int rt = 0; rt < 2; rt++)
#pragma unroll
        for (int ct = 0; ct < 8; ct++)
          acc[rt][ct] = __builtin_amdgcn_mfma_f32_16x16x32_bf16(a[rt], b[ct], acc[rt][ct], 0, 0, 0);
    }
  }

  // epilogue: C/D layout col=lane&15, row=(lane>>4)*4+reg
#pragma unroll
  for (int rt = 0; rt < 2; rt++) {
    const int rbase = n0 + w * 32 + rt * 16 + ((l >> 4) * 4);
#pragma unroll
    for (int ct = 0; ct < 8; ct++) {
      const int col = col0 + ct * 16 + (l & 15);
      const float bs = bias[col];
#pragma unroll
      for (int j = 0; j < 4; j++) {
        int r = rbase + j;
        if (r < NN) {
          float vv = acc[rt][ct][j] + bs;
          if (RELU) vv = fmaxf(vv, 0.f);
          if (WF32) outF[(size_t)r * ldo + col] = vv;
          if (WB16) outB[(size_t)r * ldo + col] = f2b(vv);
        }
      }
    }
  }
}

// ---------------- edge kernels (fp32, validated in round 0) ----------------
__global__ void k_alpha(const int* __restrict__ ei, const float* __restrict__ q,
                        const float* __restrict__ kk, float* __restrict__ alpha,
                        unsigned* __restrict__ m) {
  int tid = blockIdx.x * 256 + threadIdx.x;
  if (tid >= NE * HH) return;
  int e = tid >> 2, h = tid & 3;
  int s = ei[e], d = ei[NE + e];
  const float4* qa = (const float4*)(q + (size_t)d * DD + h * CC);
  const float4* ka = (const float4*)(kk + (size_t)s * DD + h * CC);
  float acc = 0.f;
#pragma unroll
  for (int i = 0; i < 8; i++) {
    float4 a = qa[i], b = ka[i];
    acc += a.x * b.x + a.y * b.y + a.z * b.z + a.w * b.w;
  }
  acc *= 0.17677669529663687f;  // 1/sqrt(32)
  alpha[tid] = acc;
  atomicMax(m + (size_t)d * HH + h, f2o(acc));
}

__global__ void k_expz(const int* __restrict__ ei, float* __restrict__ alpha,
                       const unsigned* __restrict__ m, float* __restrict__ z) {
  int tid = blockIdx.x * 256 + threadIdx.x;
  if (tid >= NE * HH) return;
  int e = tid >> 2, h = tid & 3;
  int d = ei[NE + e];
  float mm = o2f(m[(size_t)d * HH + h]);
  float ex = __expf(alpha[tid] - mm);
  alpha[tid] = ex;
  atomicAdd(z + (size_t)d * HH + h, ex);
}

__global__ void k_aggr(const int* __restrict__ ei, const float* __restrict__ alpha,
                       const float* __restrict__ z, const float* __restrict__ v,
                       float* __restrict__ conv) {
  int tid = blockIdx.x * 256 + threadIdx.x;  // grid sized exactly NE*32
  int e = tid >> 5, lt = tid & 31;
  int c0 = lt * 4, h = lt >> 3;
  int s = ei[e], d = ei[NE + e];
  float a = alpha[(size_t)e * HH + h] / z[(size_t)d * HH + h];
  float4 vv = *(const float4*)&v[(size_t)s * DD + c0];
  float* dst = conv + (size_t)d * DD + c0;
  atomicAdd(dst + 0, a * vv.x);
  atomicAdd(dst + 1, a * vv.y);
  atomicAdd(dst + 2, a * vv.z);
  atomicAdd(dst + 3, a * vv.w);
}

// ---------------- residual + LayerNorm (+ optional bf16 copy of output) ----------------
__global__ __launch_bounds__(256) void k_lnres(const float* __restrict__ in,
                                               const float* __restrict__ res,
                                               const float* __restrict__ lw,
                                               const float* __restrict__ lb,
                                               float* __restrict__ outF,
                                               unsigned short* __restrict__ outB) {
  const int t = threadIdx.x;
  const size_t row = blockIdx.x * 8 + (t >> 5);
  const int c0 = (t & 31) * 4;
  float4 a = *(const float4*)&in[row * DD + c0];
  float4 r = *(const float4*)&res[row * DD + c0];
  float v0 = a.x + r.x, v1 = a.y + r.y, v2 = a.z + r.z, v3 = a.w + r.w;
  float s = v0 + v1 + v2 + v3;
#pragma unroll
  for (int msk = 16; msk >= 1; msk >>= 1) s += __shfl_xor(s, msk, 64);
  const float mu = s * (1.f / 128.f);
  float d0 = v0 - mu, d1 = v1 - mu, d2 = v2 - mu, d3 = v3 - mu;
  float vs = d0 * d0 + d1 * d1 + d2 * d2 + d3 * d3;
#pragma unroll
  for (int msk = 16; msk >= 1; msk >>= 1) vs += __shfl_xor(vs, msk, 64);
  const float rs = rsqrtf(vs * (1.f / 128.f) + EPSF);
  float y0 = d0 * rs * lw[c0 + 0] + lb[c0 + 0];
  float y1 = d1 * rs * lw[c0 + 1] + lb[c0 + 1];
  float y2 = d2 * rs * lw[c0 + 2] + lb[c0 + 2];
  float y3 = d3 * rs * lw[c0 + 3] + lb[c0 + 3];
  float4 o; o.x = y0; o.y = y1; o.z = y2; o.w = y3;
  *(float4*)&outF[row * DD + c0] = o;
  if (outB) {
    ushort4 u;
    u.x = f2b(y0); u.y = f2b(y1); u.z = f2b(y2); u.w = f2b(y3);
    *(ushort4*)&outB[row * DD + c0] = u;
  }
}

extern "C" void kernel_launch(void* const* d_in, const int* in_sizes, int n_in,
                              void* d_out, int out_size, void* d_ws, size_t ws_size,
                              hipStream_t stream) {
  const float* x   = (const float*)d_in[0];
  const int*   ei  = (const int*)d_in[1];
  const float* Wq  = (const float*)d_in[2];
  const float* bq  = (const float*)d_in[3];
  const float* Wk  = (const float*)d_in[4];
  const float* bk  = (const float*)d_in[5];
  const float* Wv  = (const float*)d_in[6];
  const float* bv  = (const float*)d_in[7];
  const float* Wsk = (const float*)d_in[8];
  const float* bsk = (const float*)d_in[9];
  const float* Wo  = (const float*)d_in[10];
  const float* bo  = (const float*)d_in[11];
  const float* l1w = (const float*)d_in[12];
  const float* l1b = (const float*)d_in[13];
  const float* l2w = (const float*)d_in[14];
  const float* l2b = (const float*)d_in[15];
  const float* W1  = (const float*)d_in[16];
  const float* b1  = (const float*)d_in[17];
  const float* W2  = (const float*)d_in[18];
  const float* b2  = (const float*)d_in[19];

  // ---- workspace layout (~242 MB peak, buffers aliased through the dataflow) ----
  float* ws = (float*)d_ws;
  float* bufA = ws;                                // 51.2MB: q      -> hid(lo)
  float* bufB = bufA + (size_t)NN * DD;            // 51.2MB: kbuf   -> hid(hi)
  float* bufC = bufB + (size_t)NN * DD;            // 51.2MB: v      -> out2 (fp32)
  float* bufD = bufC + (size_t)NN * DD;            // 51.2MB: conv   -> out1 -> out3
  float* alpha = bufD + (size_t)NN * DD;           // 8MB
  float* z     = alpha + (size_t)NE * HH;          // 1.6MB
  unsigned* m  = (unsigned*)(z + (size_t)NN * HH); // 1.6MB
  unsigned short* xreg = (unsigned short*)(m + (size_t)NN * HH); // 25.6MB: xb -> convb -> out2b
  unsigned short* Wqb  = xreg + (size_t)NN * DD;
  unsigned short* Wkb  = Wqb + DD * DD;
  unsigned short* Wvb  = Wkb + DD * DD;
  unsigned short* Wskb = Wvb + DD * DD;
  unsigned short* Wob  = Wskb + DD * DD;
  unsigned short* W1b  = Wob + DD * DD;
  unsigned short* W2b  = W1b + HIDD * DD;

  float* q    = bufA;
  float* kbuf = bufB;
  float* v    = bufC;
  float* conv = bufD;
  unsigned short* xb    = xreg;
  unsigned short* convb = xreg;                    // reuses xb space (xb dead after QKV/skip)
  unsigned short* out2b = xreg;                    // reuses convb space (dead after out-proj)
  unsigned short* hid   = (unsigned short*)bufA;   // spans bufA+bufB (102.4MB, q/kbuf dead)
  float* out1 = bufD;                              // conv fp32 dead after cast to convb
  float* out2 = bufC;                              // v dead after k_aggr
  float* out3 = bufD;                              // out1 dead after lnres1
  float* outf = (float*)d_out;

  const int GX = (NN + 127) / 128;  // 782
  dim3 blk(256);

  // casts
  k_cast<<<dim3((NN * DD / 4 + 255) / 256), blk, 0, stream>>>(x, xb, NN * DD);
  k_cast<<<dim3((DD * DD / 4 + 255) / 256), blk, 0, stream>>>(Wq, Wqb, DD * DD);
  k_cast<<<dim3((DD * DD / 4 + 255) / 256), blk, 0, stream>>>(Wk, Wkb, DD * DD);
  k_cast<<<dim3((DD * DD / 4 + 255) / 256), blk, 0, stream>>>(Wv, Wvb, DD * DD);
  k_cast<<<dim3((DD * DD / 4 + 255) / 256), blk, 0, stream>>>(Wsk, Wskb, DD * DD);
  k_cast<<<dim3((DD * DD / 4 + 255) / 256), blk, 0, stream>>>(Wo, Wob, DD * DD);
  k_cast<<<dim3((HIDD * DD / 4 + 255) / 256), blk, 0, stream>>>(W1, W1b, HIDD * DD);
  k_cast<<<dim3((HIDD * DD / 4 + 255) / 256), blk, 0, stream>>>(W2, W2b, HIDD * DD);

  k_init<<<dim3((NN * HH + 255) / 256), blk, 0, stream>>>(m, z);

  // q/k/v/skip projections (skip lands in conv; edge atomics accumulate on top)
  k_mfma_gemm<128, false, true, false><<<dim3(GX, 1), blk, 0, stream>>>(xb, Wqb, bq, q, nullptr, DD);
  k_mfma_gemm<128, false, true, false><<<dim3(GX, 1), blk, 0, stream>>>(xb, Wkb, bk, kbuf, nullptr, DD);
  k_mfma_gemm<128, false, true, false><<<dim3(GX, 1), blk, 0, stream>>>(xb, Wvb, bv, v, nullptr, DD);
  k_mfma_gemm<128, false, true, false><<<dim3(GX, 1), blk, 0, stream>>>(xb, Wskb, bsk, conv, nullptr, DD);

  // attention
  k_alpha<<<dim3((NE * HH + 255) / 256), blk, 0, stream>>>(ei, q, kbuf, alpha, m);
  k_expz<<<dim3((NE * HH + 255) / 256), blk, 0, stream>>>(ei, alpha, m, z);
  k_aggr<<<dim3(NE * 32 / 256), blk, 0, stream>>>(ei, alpha, z, v, conv);

  // out projection + LN1  (q,kbuf now dead; conv -> convb, out1 overwrites conv)
  k_cast<<<dim3((NN * DD / 4 + 255) / 256), blk, 0, stream>>>(conv, convb, NN * DD);
  k_mfma_gemm<128, false, true, false><<<dim3(GX, 1), blk, 0, stream>>>(convb, Wob, bo, out1, nullptr, DD);
  k_lnres<<<dim3(NN / 8), blk, 0, stream>>>(out1, x, l1w, l1b, out2, out2b);

  // FFN + LN2  (hid lives in bufA+bufB)
  k_mfma_gemm<128, true, false, true><<<dim3(GX, 4), blk, 0, stream>>>(out2b, W1b, b1, nullptr, hid, HIDD);
  k_mfma_gemm<512, false, true, false><<<dim3(GX, 1), blk, 0, stream>>>(hid, W2b, b2, out3, nullptr, DD);
  k_lnres<<<dim3(NN / 8), blk, 0, stream>>>(out3, out2, l2w, l2b, outf, nullptr);
}

// Round 4
// 482.036 us; speedup vs baseline: 7.0535x; 2.7235x over previous
//
#include <hip/hip_runtime.h>

#define NN   100000
#define NE   500000
#define DD   128
#define HH   4
#define CC   32
#define HIDD 512
#define EPSF 1e-5f

typedef __bf16 bf16x8 __attribute__((ext_vector_type(8)));
typedef float  f32x4  __attribute__((ext_vector_type(4)));

__device__ __forceinline__ unsigned short f2b(float f) {
  unsigned u = __float_as_uint(f);
  unsigned r = (u + 0x7FFFu + ((u >> 16) & 1)) >> 16;
  return (unsigned short)r;
}

// fp32 -> bf16 cast, 4 elems/thread
__global__ void k_cast(const float* __restrict__ src, unsigned short* __restrict__ dst, int n) {
  int i = (blockIdx.x * 256 + threadIdx.x) * 4;
  if (i >= n) return;
  float4 v = *(const float4*)&src[i];
  ushort4 o;
  o.x = f2b(v.x); o.y = f2b(v.y); o.z = f2b(v.z); o.w = f2b(v.w);
  *(ushort4*)&dst[i] = o;
}

// strided cast: conv lives in qkvs[:, 384:512]
__global__ void k_cast_conv(const float* __restrict__ qkvs, unsigned short* __restrict__ dst) {
  int i = blockIdx.x * 256 + threadIdx.x;  // NN*32 float4 groups
  int node = i >> 5, c4 = i & 31;
  float4 v = *(const float4*)&qkvs[(size_t)node * 512 + 384 + c4 * 4];
  ushort4 o;
  o.x = f2b(v.x); o.y = f2b(v.y); o.z = f2b(v.z); o.w = f2b(v.w);
  *(ushort4*)&dst[(size_t)node * DD + c4 * 4] = o;
}

__global__ void k_packb(const float* __restrict__ bq, const float* __restrict__ bk,
                        const float* __restrict__ bv, const float* __restrict__ bs,
                        float* __restrict__ out) {
  int i = threadIdx.x;  // 512
  const float* srcs[4] = {bq, bk, bv, bs};
  out[i] = srcs[i >> 7][i & 127];
}

// ---------------- CSR build ----------------
__global__ void k_zero_cnt(int* __restrict__ cnt) {
  int i = blockIdx.x * 256 + threadIdx.x;
  if (i < NN) cnt[i] = 0;
}
__global__ void k_count(const int* __restrict__ ei, int* __restrict__ cnt) {
  int e = blockIdx.x * 256 + threadIdx.x;
  if (e < NE) atomicAdd(&cnt[ei[NE + e]], 1);
}
__global__ void k_scan1(const int* __restrict__ cnt, int* __restrict__ rowptr, int* __restrict__ part) {
  __shared__ int sh[256];
  int i = blockIdx.x * 256 + threadIdx.x;
  int v = (i < NN) ? cnt[i] : 0;
  sh[threadIdx.x] = v; __syncthreads();
  for (int off = 1; off < 256; off <<= 1) {
    int t = (threadIdx.x >= off) ? sh[threadIdx.x - off] : 0;
    __syncthreads();
    sh[threadIdx.x] += t;
    __syncthreads();
  }
  if (i < NN) rowptr[i] = sh[threadIdx.x] - v;  // exclusive
  if (threadIdx.x == 255) part[blockIdx.x] = sh[255];
}
__global__ void k_scan2(const int* __restrict__ part, int* __restrict__ partx) {
  __shared__ int sh[512];
  int t = threadIdx.x;
  int v = (t < 391) ? part[t] : 0;
  sh[t] = v; __syncthreads();
  for (int off = 1; off < 512; off <<= 1) {
    int u = (t >= off) ? sh[t - off] : 0;
    __syncthreads();
    sh[t] += u;
    __syncthreads();
  }
  partx[t] = sh[t] - v;
}
__global__ void k_scan3(int* __restrict__ rowptr, const int* __restrict__ partx, int* __restrict__ cnt) {
  int i = blockIdx.x * 256 + threadIdx.x;
  if (i < NN) {
    int r = rowptr[i] + partx[i >> 8];
    rowptr[i] = r;
    cnt[i] = r;
  }
  if (i == 0) rowptr[NN] = NE;
}
__global__ void k_scatter(const int* __restrict__ ei, int* __restrict__ cnt, int* __restrict__ csr_src) {
  int e = blockIdx.x * 256 + threadIdx.x;
  if (e >= NE) return;
  int d = ei[NE + e];
  int pos = atomicAdd(&cnt[d], 1);
  csr_src[pos] = ei[e];
}

// ---------------- fused attention: logits + segment softmax + aggregate + skip ----------------
// qkvs layout [N,512]: q 0:128, k 128:256, v 256:384, skip->conv 384:512
// one node per 32-lane half-wave; 8 nodes per 256-block
__global__ __launch_bounds__(256) void k_attn(const int* __restrict__ csr_src,
                                              const int* __restrict__ rowptr,
                                              float* qkvs,
                                              float* __restrict__ alpha) {
  const int l = threadIdx.x & 31;
  const int node = blockIdx.x * 8 + (threadIdx.x >> 5);  // grid exact: 12500*8
  const int row0 = rowptr[node], row1 = rowptr[node + 1];
  const int h8 = l >> 3;  // this lane's head in pass 1/3
  const float4 qv = *(const float4*)&qkvs[(size_t)node * 512 + l * 4];
  float mmax = -3.4e38f;
  // pass 1: logits + running max
  for (int p = row0; p < row1; ++p) {
    int s = csr_src[p];
    float4 kv = *(const float4*)&qkvs[(size_t)s * 512 + 128 + l * 4];
    float d = qv.x * kv.x + qv.y * kv.y + qv.z * kv.z + qv.w * kv.w;
    d += __shfl_xor(d, 1, 32);
    d += __shfl_xor(d, 2, 32);
    d += __shfl_xor(d, 4, 32);
    d *= 0.17677669529663687f;
    mmax = fmaxf(mmax, d);
    if ((l & 7) == 0) alpha[(size_t)p * 4 + h8] = d;
  }
  // pass 2: exp + z   (lane handles head myh = l&3, edge pb + l/4; addr = pb*4 + l, contiguous)
  const int myh = l & 3;
  const float mh = __shfl(mmax, myh * 8, 32);
  float zacc = 0.f;
  for (int pb = row0; pb < row1; pb += 8) {
    int idx = pb + (l >> 2);
    float e = 0.f;
    if (idx < row1) {
      float a = alpha[(size_t)idx * 4 + myh];
      e = __expf(a - mh);
      alpha[(size_t)idx * 4 + myh] = e;
    }
    zacc += e;
  }
  zacc += __shfl_xor(zacc, 4, 32);
  zacc += __shfl_xor(zacc, 8, 32);
  zacc += __shfl_xor(zacc, 16, 32);
  const float rzh = 1.f / __shfl(zacc, h8, 4);  // z of this lane's pass-3 head
  // pass 3: conv = skip + sum a*v
  float4 acc = *(const float4*)&qkvs[(size_t)node * 512 + 384 + l * 4];
  for (int p = row0; p < row1; ++p) {
    int s = csr_src[p];
    float w = alpha[(size_t)p * 4 + h8] * rzh;
    float4 vv = *(const float4*)&qkvs[(size_t)s * 512 + 256 + l * 4];
    acc.x += w * vv.x; acc.y += w * vv.y; acc.z += w * vv.z; acc.w += w * vv.w;
  }
  *(float4*)&qkvs[(size_t)node * 512 + 384 + l * 4] = acc;
}

// ---------------- MFMA GEMM (128x128 tile, 4 waves) ----------------
template <int KTOT, bool RELU, bool WF32, bool WB16>
__global__ __launch_bounds__(256) void k_mfma_gemm(const unsigned short* __restrict__ A,
                                                   const unsigned short* __restrict__ W,
                                                   const float* __restrict__ bias,
                                                   float* __restrict__ outF,
                                                   unsigned short* __restrict__ outB,
                                                   int ldo) {
  __shared__ unsigned short As[128 * 128];
  __shared__ unsigned short Ws[128 * 128];
  const int t = threadIdx.x;
  const int n0 = blockIdx.x * 128;
  const int col0 = blockIdx.y * 128;
  const int w = t >> 6, l = t & 63;

  f32x4 acc[2][8] = {};

  for (int kc = 0; kc < KTOT / 128; ++kc) {
    __syncthreads();
#pragma unroll
    for (int i = 0; i < 8; i++) {
      int chunk = t + i * 256;
      int row = chunk >> 4, c16 = chunk & 15;
      uint4 val = make_uint4(0u, 0u, 0u, 0u);
      int gr = n0 + row;
      if (gr < NN) val = *(const uint4*)(A + (size_t)gr * KTOT + kc * 128 + c16 * 8);
      *(uint4*)&As[row * 128 + ((c16 ^ (row & 7)) * 8)] = val;
    }
#pragma unroll
    for (int i = 0; i < 8; i++) {
      int chunk = t + i * 256;
      int row = chunk >> 4, c16 = chunk & 15;
      uint4 val = *(const uint4*)(W + (size_t)(col0 + row) * KTOT + kc * 128 + c16 * 8);
      *(uint4*)&Ws[row * 128 + ((c16 ^ (row & 7)) * 8)] = val;
    }
    __syncthreads();
#pragma unroll
    for (int ks = 0; ks < 4; ks++) {
      bf16x8 a[2], b[8];
      const int c16 = ks * 4 + (l >> 4);
#pragma unroll
      for (int rt = 0; rt < 2; rt++) {
        int row = w * 32 + rt * 16 + (l & 15);
        a[rt] = *(const bf16x8*)&As[row * 128 + ((c16 ^ (row & 7)) * 8)];
      }
#pragma unroll
      for (int ct = 0; ct < 8; ct++) {
        int row = ct * 16 + (l & 15);
        b[ct] = *(const bf16x8*)&Ws[row * 128 + ((c16 ^ (row & 7)) * 8)];
      }
#pragma unroll
      for (int rt = 0; rt < 2; rt++)
#pragma unroll
        for (int ct = 0; ct < 8; ct++)
          acc[rt][ct] = __builtin_amdgcn_mfma_f32_16x16x32_bf16(a[rt], b[ct], acc[rt][ct], 0, 0, 0);
    }
  }

#pragma unroll
  for (int rt = 0; rt < 2; rt++) {
    const int rbase = n0 + w * 32 + rt * 16 + ((l >> 4) * 4);
#pragma unroll
    for (int ct = 0; ct < 8; ct++) {
      const int col = col0 + ct * 16 + (l & 15);
      const float bs = bias[col];
#pragma unroll
      for (int j = 0; j < 4; j++) {
        int r = rbase + j;
        if (r < NN) {
          float vv = acc[rt][ct][j] + bs;
          if (RELU) vv = fmaxf(vv, 0.f);
          if (WF32) outF[(size_t)r * ldo + col] = vv;
          if (WB16) outB[(size_t)r * ldo + col] = f2b(vv);
        }
      }
    }
  }
}

// ---------------- residual + LayerNorm (+ optional bf16 copy) ----------------
__global__ __launch_bounds__(256) void k_lnres(const float* __restrict__ in,
                                               const float* __restrict__ res,
                                               const float* __restrict__ lw,
                                               const float* __restrict__ lb,
                                               float* __restrict__ outF,
                                               unsigned short* __restrict__ outB) {
  const int t = threadIdx.x;
  const size_t row = blockIdx.x * 8 + (t >> 5);
  const int c0 = (t & 31) * 4;
  float4 a = *(const float4*)&in[row * DD + c0];
  float4 r = *(const float4*)&res[row * DD + c0];
  float v0 = a.x + r.x, v1 = a.y + r.y, v2 = a.z + r.z, v3 = a.w + r.w;
  float s = v0 + v1 + v2 + v3;
#pragma unroll
  for (int msk = 16; msk >= 1; msk >>= 1) s += __shfl_xor(s, msk, 64);
  const float mu = s * (1.f / 128.f);
  float d0 = v0 - mu, d1 = v1 - mu, d2 = v2 - mu, d3 = v3 - mu;
  float vs = d0 * d0 + d1 * d1 + d2 * d2 + d3 * d3;
#pragma unroll
  for (int msk = 16; msk >= 1; msk >>= 1) vs += __shfl_xor(vs, msk, 64);
  const float rs = rsqrtf(vs * (1.f / 128.f) + EPSF);
  float y0 = d0 * rs * lw[c0 + 0] + lb[c0 + 0];
  float y1 = d1 * rs * lw[c0 + 1] + lb[c0 + 1];
  float y2 = d2 * rs * lw[c0 + 2] + lb[c0 + 2];
  float y3 = d3 * rs * lw[c0 + 3] + lb[c0 + 3];
  float4 o; o.x = y0; o.y = y1; o.z = y2; o.w = y3;
  *(float4*)&outF[row * DD + c0] = o;
  if (outB) {
    ushort4 u;
    u.x = f2b(y0); u.y = f2b(y1); u.z = f2b(y2); u.w = f2b(y3);
    *(ushort4*)&outB[row * DD + c0] = u;
  }
}

extern "C" void kernel_launch(void* const* d_in, const int* in_sizes, int n_in,
                              void* d_out, int out_size, void* d_ws, size_t ws_size,
                              hipStream_t stream) {
  const float* x   = (const float*)d_in[0];
  const int*   ei  = (const int*)d_in[1];
  const float* Wq  = (const float*)d_in[2];
  const float* bq  = (const float*)d_in[3];
  const float* Wk  = (const float*)d_in[4];
  const float* bk  = (const float*)d_in[5];
  const float* Wv  = (const float*)d_in[6];
  const float* bv  = (const float*)d_in[7];
  const float* Wsk = (const float*)d_in[8];
  const float* bsk = (const float*)d_in[9];
  const float* Wo  = (const float*)d_in[10];
  const float* bo  = (const float*)d_in[11];
  const float* l1w = (const float*)d_in[12];
  const float* l1b = (const float*)d_in[13];
  const float* l2w = (const float*)d_in[14];
  const float* l2b = (const float*)d_in[15];
  const float* W1  = (const float*)d_in[16];
  const float* b1  = (const float*)d_in[17];
  const float* W2  = (const float*)d_in[18];
  const float* b2  = (const float*)d_in[19];

  // ---- workspace layout (~241.6 MB peak) ----
  float* qkvs = (float*)d_ws;                                       // [N,512] fp32, 204.8MB
  unsigned short* xreg = (unsigned short*)(qkvs + (size_t)NN * 512); // 25.6MB: xb -> convb -> out2b
  unsigned short* Wqb  = xreg + (size_t)NN * DD;                    // q|k|v|skip weights contiguous
  unsigned short* Wkb  = Wqb + DD * DD;
  unsigned short* Wvb  = Wkb + DD * DD;
  unsigned short* Wskb = Wvb + DD * DD;
  unsigned short* Wob  = Wskb + DD * DD;
  unsigned short* W1b  = Wob + DD * DD;
  unsigned short* W2b  = W1b + (size_t)HIDD * DD;
  float* bias512 = (float*)(W2b + (size_t)HIDD * DD);               // 2KB
  float* alpha   = bias512 + 512;                                   // E*4 fp32, 8MB
  int* csr_src   = (int*)(alpha + (size_t)NE * HH);                 // 2MB
  int* rowptr    = csr_src + NE;                                    // N+1
  int* cnt       = rowptr + NN + 1;                                 // N
  int* part      = cnt + NN;                                        // 391
  int* partx     = part + 512;                                      // 512

  // phase-2 aliases inside qkvs region
  float* out1 = qkvs;                                          // 0..51.2MB
  float* out2 = qkvs + (size_t)NN * DD;                        // 51.2..102.4MB
  unsigned short* hid = (unsigned short*)(qkvs + (size_t)2 * NN * DD);  // 102.4..204.8MB
  float* out3 = qkvs;                                          // reuse out1 (dead)
  unsigned short* xb    = xreg;
  unsigned short* convb = xreg;
  unsigned short* out2b = xreg;
  float* outf = (float*)d_out;

  const int GX = (NN + 127) / 128;  // 782
  dim3 blk(256);

  // casts + bias pack
  k_cast<<<dim3(12500), blk, 0, stream>>>(x, xb, NN * DD);
  k_cast<<<dim3(16), blk, 0, stream>>>(Wq, Wqb, DD * DD);
  k_cast<<<dim3(16), blk, 0, stream>>>(Wk, Wkb, DD * DD);
  k_cast<<<dim3(16), blk, 0, stream>>>(Wv, Wvb, DD * DD);
  k_cast<<<dim3(16), blk, 0, stream>>>(Wsk, Wskb, DD * DD);
  k_cast<<<dim3(16), blk, 0, stream>>>(Wo, Wob, DD * DD);
  k_cast<<<dim3(64), blk, 0, stream>>>(W1, W1b, HIDD * DD);
  k_cast<<<dim3(64), blk, 0, stream>>>(W2, W2b, HIDD * DD);
  k_packb<<<dim3(1), dim3(512), 0, stream>>>(bq, bk, bv, bsk, bias512);

  // CSR build
  k_zero_cnt<<<dim3(391), blk, 0, stream>>>(cnt);
  k_count<<<dim3(1954), blk, 0, stream>>>(ei, cnt);
  k_scan1<<<dim3(391), blk, 0, stream>>>(cnt, rowptr, part);
  k_scan2<<<dim3(1), dim3(512), 0, stream>>>(part, partx);
  k_scan3<<<dim3(391), blk, 0, stream>>>(rowptr, partx, cnt);
  k_scatter<<<dim3(1954), blk, 0, stream>>>(ei, cnt, csr_src);

  // fused q|k|v|skip projection: qkvs[N,512]
  k_mfma_gemm<128, false, true, false><<<dim3(GX, 4), blk, 0, stream>>>(xb, Wqb, bias512, qkvs, nullptr, 512);

  // fused attention (writes conv into skip slot)
  k_attn<<<dim3(12500), blk, 0, stream>>>(csr_src, rowptr, qkvs, alpha);

  // out projection + LN1
  k_cast_conv<<<dim3(12500), blk, 0, stream>>>(qkvs, convb);
  k_mfma_gemm<128, false, true, false><<<dim3(GX, 1), blk, 0, stream>>>(convb, Wob, bo, out1, nullptr, DD);
  k_lnres<<<dim3(12500), blk, 0, stream>>>(out1, x, l1w, l1b, out2, out2b);

  // FFN + LN2
  k_mfma_gemm<128, true, false, true><<<dim3(GX, 4), blk, 0, stream>>>(out2b, W1b, b1, nullptr, hid, HIDD);
  k_mfma_gemm<512, false, true, false><<<dim3(GX, 1), blk, 0, stream>>>(hid, W2b, b2, out3, nullptr, DD);
  k_lnres<<<dim3(12500), blk, 0, stream>>>(out3, out2, l2w, l2b, outf, nullptr);
}

// Round 5
// 442.311 us; speedup vs baseline: 7.6870x; 1.0898x over previous
//
#include <hip/hip_runtime.h>

#define NN   100000
#define NE   500000
#define DD   128
#define HH   4
#define CC   32
#define HIDD 512
#define EPSF 1e-5f

typedef __bf16 bf16x8 __attribute__((ext_vector_type(8)));
typedef float  f32x4  __attribute__((ext_vector_type(4)));

__device__ __forceinline__ unsigned short f2b(float f) {
  unsigned u = __float_as_uint(f);
  unsigned r = (u + 0x7FFFu + ((u >> 16) & 1)) >> 16;
  return (unsigned short)r;
}
__device__ __forceinline__ float b2f(unsigned short s) {
  return __uint_as_float(((unsigned)s) << 16);
}

// fp32 -> bf16 cast, 4 elems/thread
__global__ void k_cast(const float* __restrict__ src, unsigned short* __restrict__ dst, int n) {
  int i = (blockIdx.x * 256 + threadIdx.x) * 4;
  if (i >= n) return;
  float4 v = *(const float4*)&src[i];
  ushort4 o;
  o.x = f2b(v.x); o.y = f2b(v.y); o.z = f2b(v.z); o.w = f2b(v.w);
  *(ushort4*)&dst[i] = o;
}

__global__ void k_packb(const float* __restrict__ bq, const float* __restrict__ bk,
                        const float* __restrict__ bv, const float* __restrict__ bs,
                        float* __restrict__ out) {
  int i = threadIdx.x;  // 512
  const float* srcs[4] = {bq, bk, bv, bs};
  out[i] = srcs[i >> 7][i & 127];
}

// ---------------- CSR build ----------------
__global__ void k_zero_cnt(int* __restrict__ cnt) {
  int i = blockIdx.x * 256 + threadIdx.x;
  if (i < NN) cnt[i] = 0;
}
__global__ void k_count(const int* __restrict__ ei, int* __restrict__ cnt) {
  int e = blockIdx.x * 256 + threadIdx.x;
  if (e < NE) atomicAdd(&cnt[ei[NE + e]], 1);
}
__global__ void k_scan1(const int* __restrict__ cnt, int* __restrict__ rowptr, int* __restrict__ part) {
  __shared__ int sh[256];
  int i = blockIdx.x * 256 + threadIdx.x;
  int v = (i < NN) ? cnt[i] : 0;
  sh[threadIdx.x] = v; __syncthreads();
  for (int off = 1; off < 256; off <<= 1) {
    int t = (threadIdx.x >= off) ? sh[threadIdx.x - off] : 0;
    __syncthreads();
    sh[threadIdx.x] += t;
    __syncthreads();
  }
  if (i < NN) rowptr[i] = sh[threadIdx.x] - v;  // exclusive
  if (threadIdx.x == 255) part[blockIdx.x] = sh[255];
}
__global__ void k_scan2(const int* __restrict__ part, int* __restrict__ partx) {
  __shared__ int sh[512];
  int t = threadIdx.x;
  int v = (t < 391) ? part[t] : 0;
  sh[t] = v; __syncthreads();
  for (int off = 1; off < 512; off <<= 1) {
    int u = (t >= off) ? sh[t - off] : 0;
    __syncthreads();
    sh[t] += u;
    __syncthreads();
  }
  partx[t] = sh[t] - v;
}
__global__ void k_scan3(int* __restrict__ rowptr, const int* __restrict__ partx, int* __restrict__ cnt) {
  int i = blockIdx.x * 256 + threadIdx.x;
  if (i < NN) {
    int r = rowptr[i] + partx[i >> 8];
    rowptr[i] = r;
    cnt[i] = r;
  }
  if (i == 0) rowptr[NN] = NE;
}
__global__ void k_scatter(const int* __restrict__ ei, int* __restrict__ cnt, int* __restrict__ csr_src) {
  int e = blockIdx.x * 256 + threadIdx.x;
  if (e >= NE) return;
  int d = ei[NE + e];
  int pos = atomicAdd(&cnt[d], 1);
  csr_src[pos] = ei[e];
}

// ---------------- shared MFMA core ----------------
#define MFMA_CORE(A_EXPR, W_EXPR, KTOT)                                                  \
  __shared__ unsigned short As[128 * 128];                                               \
  __shared__ unsigned short Ws[128 * 128];                                               \
  const int t = threadIdx.x;                                                             \
  const int n0 = blockIdx.x * 128;                                                       \
  const int w = t >> 6, l = t & 63;                                                      \
  f32x4 acc[2][8] = {};                                                                  \
  for (int kc = 0; kc < (KTOT) / 128; ++kc) {                                            \
    __syncthreads();                                                                     \
    _Pragma("unroll") for (int i = 0; i < 8; i++) {                                      \
      int chunk = t + i * 256;                                                           \
      int row = chunk >> 4, c16 = chunk & 15;                                            \
      uint4 val = make_uint4(0u, 0u, 0u, 0u);                                            \
      int gr = n0 + row;                                                                 \
      if (gr < NN) val = *(const uint4*)(A_EXPR);                                        \
      *(uint4*)&As[row * 128 + ((c16 ^ (row & 7)) * 8)] = val;                           \
    }                                                                                    \
    _Pragma("unroll") for (int i = 0; i < 8; i++) {                                      \
      int chunk = t + i * 256;                                                           \
      int row = chunk >> 4, c16 = chunk & 15;                                            \
      uint4 val = *(const uint4*)(W_EXPR);                                               \
      *(uint4*)&Ws[row * 128 + ((c16 ^ (row & 7)) * 8)] = val;                           \
    }                                                                                    \
    __syncthreads();                                                                     \
    _Pragma("unroll") for (int ks = 0; ks < 4; ks++) {                                   \
      bf16x8 a[2], b[8];                                                                 \
      const int c16 = ks * 4 + (l >> 4);                                                 \
      _Pragma("unroll") for (int rt = 0; rt < 2; rt++) {                                 \
        int row = w * 32 + rt * 16 + (l & 15);                                           \
        a[rt] = *(const bf16x8*)&As[row * 128 + ((c16 ^ (row & 7)) * 8)];                \
      }                                                                                  \
      _Pragma("unroll") for (int ct = 0; ct < 8; ct++) {                                 \
        int row = ct * 16 + (l & 15);                                                    \
        b[ct] = *(const bf16x8*)&Ws[row * 128 + ((c16 ^ (row & 7)) * 8)];                \
      }                                                                                  \
      _Pragma("unroll") for (int rt = 0; rt < 2; rt++)                                   \
        _Pragma("unroll") for (int ct = 0; ct < 8; ct++)                                 \
          acc[rt][ct] = __builtin_amdgcn_mfma_f32_16x16x32_bf16(a[rt], b[ct], acc[rt][ct], 0, 0, 0); \
    }                                                                                    \
  }

// qkv+skip projection: y=0 -> qf fp32 [N,128]; y=1/2 -> kvb bf16 [N,256] (k|v); y=3 -> skipf fp32
__global__ __launch_bounds__(256) void k_gemm_qkvs(const unsigned short* __restrict__ A,
                                                   const unsigned short* __restrict__ Wp,
                                                   const float* __restrict__ bias512,
                                                   float* __restrict__ qf,
                                                   unsigned short* __restrict__ kvb,
                                                   float* __restrict__ skipf) {
  const int col0 = blockIdx.y * 128;
  MFMA_CORE(A + (size_t)gr * 128 + c16 * 8,
            Wp + (size_t)(col0 + row) * 128 + c16 * 8, 128)
  const int y = blockIdx.y;
#pragma unroll
  for (int rt = 0; rt < 2; rt++) {
    const int rbase = n0 + w * 32 + rt * 16 + ((l >> 4) * 4);
#pragma unroll
    for (int ct = 0; ct < 8; ct++) {
      const int col = ct * 16 + (l & 15);
      const float bs = bias512[col0 + col];
#pragma unroll
      for (int j = 0; j < 4; j++) {
        int r = rbase + j;
        if (r < NN) {
          float vv = acc[rt][ct][j] + bs;
          if (y == 0)      qf[(size_t)r * 128 + col] = vv;
          else if (y == 1) kvb[(size_t)r * 256 + col] = f2b(vv);
          else if (y == 2) kvb[(size_t)r * 256 + 128 + col] = f2b(vv);
          else             skipf[(size_t)r * 128 + col] = vv;
        }
      }
    }
  }
}

// generic GEMM (used for FFN1): out bf16, optional relu
template <int KTOT, bool RELU>
__global__ __launch_bounds__(256) void k_mfma_gemm(const unsigned short* __restrict__ A,
                                                   const unsigned short* __restrict__ W,
                                                   const float* __restrict__ bias,
                                                   unsigned short* __restrict__ outB,
                                                   int ldo) {
  const int col0 = blockIdx.y * 128;
  MFMA_CORE(A + (size_t)gr * KTOT + kc * 128 + c16 * 8,
            W + (size_t)(col0 + row) * KTOT + kc * 128 + c16 * 8, KTOT)
#pragma unroll
  for (int rt = 0; rt < 2; rt++) {
    const int rbase = n0 + w * 32 + rt * 16 + ((l >> 4) * 4);
#pragma unroll
    for (int ct = 0; ct < 8; ct++) {
      const int col = col0 + ct * 16 + (l & 15);
      const float bs = bias[col];
#pragma unroll
      for (int j = 0; j < 4; j++) {
        int r = rbase + j;
        if (r < NN) {
          float vv = acc[rt][ct][j] + bs;
          if (RELU) vv = fmaxf(vv, 0.f);
          outB[(size_t)r * ldo + col] = f2b(vv);
        }
      }
    }
  }
}

// GEMM + residual + LayerNorm fused epilogue (128-col output == full row per tile)
template <int KTOT, bool WB16>
__global__ __launch_bounds__(256) void k_gemm_ln(const unsigned short* __restrict__ A,
                                                 const unsigned short* __restrict__ W,
                                                 const float* __restrict__ bias,
                                                 const float* __restrict__ res,
                                                 const float* __restrict__ lw,
                                                 const float* __restrict__ lb,
                                                 float* __restrict__ outF,
                                                 unsigned short* __restrict__ outB) {
  MFMA_CORE(A + (size_t)gr * KTOT + kc * 128 + c16 * 8,
            W + (size_t)row * KTOT + kc * 128 + c16 * 8, KTOT)
  const int colL = l & 15;
  // bias + residual into acc
#pragma unroll
  for (int rt = 0; rt < 2; rt++) {
    const int lrow0 = n0 + w * 32 + rt * 16 + ((l >> 4) * 4);
#pragma unroll
    for (int ct = 0; ct < 8; ct++) {
      const int col = ct * 16 + colL;
      const float bs = bias[col];
#pragma unroll
      for (int j = 0; j < 4; j++) {
        int grow = lrow0 + j;
        float rv = (grow < NN) ? res[(size_t)grow * DD + col] : 0.f;
        acc[rt][ct][j] += bs + rv;
      }
    }
  }
  // per-row LayerNorm: row's 128 cols = 8 ct regs x 16 lanes (same l>>4 group)
#pragma unroll
  for (int rt = 0; rt < 2; rt++) {
    const int lrow0 = n0 + w * 32 + rt * 16 + ((l >> 4) * 4);
#pragma unroll
    for (int j = 0; j < 4; j++) {
      float s = 0.f;
#pragma unroll
      for (int ct = 0; ct < 8; ct++) s += acc[rt][ct][j];
      s += __shfl_xor(s, 1, 64); s += __shfl_xor(s, 2, 64);
      s += __shfl_xor(s, 4, 64); s += __shfl_xor(s, 8, 64);
      const float mu = s * (1.f / 128.f);
      float vs = 0.f;
#pragma unroll
      for (int ct = 0; ct < 8; ct++) { float d = acc[rt][ct][j] - mu; vs += d * d; }
      vs += __shfl_xor(vs, 1, 64); vs += __shfl_xor(vs, 2, 64);
      vs += __shfl_xor(vs, 4, 64); vs += __shfl_xor(vs, 8, 64);
      const float rs = rsqrtf(vs * (1.f / 128.f) + EPSF);
      const int grow = lrow0 + j;
      if (grow < NN) {
#pragma unroll
        for (int ct = 0; ct < 8; ct++) {
          const int col = ct * 16 + colL;
          float yv = (acc[rt][ct][j] - mu) * rs * lw[col] + lb[col];
          outF[(size_t)grow * DD + col] = yv;
          if (WB16) outB[(size_t)grow * DD + col] = f2b(yv);
        }
      }
    }
  }
}

// ---------------- fused attention (bf16 k/v gathers, bf16 conv out) ----------------
// qf fp32 [N,128]; kvb bf16 [N,256] (k 0:128, v 128:256); skipf fp32 [N,128]; convb bf16 [N,128]
__global__ __launch_bounds__(256) void k_attn(const int* __restrict__ csr_src,
                                              const int* __restrict__ rowptr,
                                              const float* __restrict__ qf,
                                              const unsigned short* __restrict__ kvb,
                                              const float* __restrict__ skipf,
                                              float* __restrict__ alpha,
                                              unsigned short* __restrict__ convb) {
  const int l = threadIdx.x & 31;
  const int node = blockIdx.x * 8 + (threadIdx.x >> 5);  // grid exact: 12500*8
  const int row0 = rowptr[node], row1 = rowptr[node + 1];
  const int h8 = l >> 3;
  const float4 qv = *(const float4*)&qf[(size_t)node * 128 + l * 4];
  float mmax = -3.4e38f;
  // pass 1: logits + running max
  for (int p = row0; p < row1; ++p) {
    int s = csr_src[p];
    ushort4 kr = *(const ushort4*)&kvb[(size_t)s * 256 + l * 4];
    float d = qv.x * b2f(kr.x) + qv.y * b2f(kr.y) + qv.z * b2f(kr.z) + qv.w * b2f(kr.w);
    d += __shfl_xor(d, 1, 32);
    d += __shfl_xor(d, 2, 32);
    d += __shfl_xor(d, 4, 32);
    d *= 0.17677669529663687f;
    mmax = fmaxf(mmax, d);
    if ((l & 7) == 0) alpha[(size_t)p * 4 + h8] = d;
  }
  // pass 2: exp + z
  const int myh = l & 3;
  const float mh = __shfl(mmax, myh * 8, 32);
  float zacc = 0.f;
  for (int pb = row0; pb < row1; pb += 8) {
    int idx = pb + (l >> 2);
    float e = 0.f;
    if (idx < row1) {
      float a = alpha[(size_t)idx * 4 + myh];
      e = __expf(a - mh);
      alpha[(size_t)idx * 4 + myh] = e;
    }
    zacc += e;
  }
  zacc += __shfl_xor(zacc, 4, 32);
  zacc += __shfl_xor(zacc, 8, 32);
  zacc += __shfl_xor(zacc, 16, 32);
  const float rzh = 1.f / __shfl(zacc, h8, 4);
  // pass 3: conv = skip + sum a*v  -> bf16
  float4 acc = *(const float4*)&skipf[(size_t)node * 128 + l * 4];
  for (int p = row0; p < row1; ++p) {
    int s = csr_src[p];
    float wgt = alpha[(size_t)p * 4 + h8] * rzh;
    ushort4 vr = *(const ushort4*)&kvb[(size_t)s * 256 + 128 + l * 4];
    acc.x += wgt * b2f(vr.x); acc.y += wgt * b2f(vr.y);
    acc.z += wgt * b2f(vr.z); acc.w += wgt * b2f(vr.w);
  }
  ushort4 o;
  o.x = f2b(acc.x); o.y = f2b(acc.y); o.z = f2b(acc.z); o.w = f2b(acc.w);
  *(ushort4*)&convb[(size_t)node * 128 + l * 4] = o;
}

extern "C" void kernel_launch(void* const* d_in, const int* in_sizes, int n_in,
                              void* d_out, int out_size, void* d_ws, size_t ws_size,
                              hipStream_t stream) {
  const float* x   = (const float*)d_in[0];
  const int*   ei  = (const int*)d_in[1];
  const float* Wq  = (const float*)d_in[2];
  const float* bq  = (const float*)d_in[3];
  const float* Wk  = (const float*)d_in[4];
  const float* bk  = (const float*)d_in[5];
  const float* Wv  = (const float*)d_in[6];
  const float* bv  = (const float*)d_in[7];
  const float* Wsk = (const float*)d_in[8];
  const float* bsk = (const float*)d_in[9];
  const float* Wo  = (const float*)d_in[10];
  const float* bo  = (const float*)d_in[11];
  const float* l1w = (const float*)d_in[12];
  const float* l1b = (const float*)d_in[13];
  const float* l2w = (const float*)d_in[14];
  const float* l2b = (const float*)d_in[15];
  const float* W1  = (const float*)d_in[16];
  const float* b1  = (const float*)d_in[17];
  const float* W2  = (const float*)d_in[18];
  const float* b2  = (const float*)d_in[19];

  // ---- workspace layout (float units; ~216 MB peak) ----
  const size_t ND = (size_t)NN * DD;  // 12.8M
  float* ws = (float*)d_ws;
  float*          qf    = ws;                          // [0, ND)            fp32
  unsigned short* kvb   = (unsigned short*)(ws + ND);  // [ND, 2ND) floats   bf16 [N,256]
  float*          skipf = ws + 2 * ND;                 // [2ND, 3ND)         fp32
  unsigned short* xb    = (unsigned short*)(ws + 3 * ND);          // NN*128 bf16 = ND/2 floats
  float*          alpha = ws + 3 * ND + ND / 2;                    // NE*4 fp32 (2M floats)
  unsigned short* convb = (unsigned short*)(alpha + (size_t)NE * HH); // ND/2 floats
  int* csr_src = (int*)(convb + ND);                   // NE ints
  int* rowptr  = csr_src + NE;
  int* cnt     = rowptr + NN + 1;
  int* part    = cnt + NN;
  int* partx   = part + 512;
  unsigned short* Wqkvs = (unsigned short*)(partx + 512);  // packed [512,128] bf16
  unsigned short* Wob   = Wqkvs + 512 * DD;
  unsigned short* W1b   = Wob + DD * DD;
  unsigned short* W2b   = W1b + (size_t)HIDD * DD;
  float* bias512        = (float*)(W2b + (size_t)HIDD * DD);

  // phase-2 aliases (qf/kvb/skipf/xb dead in sequence)
  float*          out2  = qf;                                   // [0, ND)
  unsigned short* out2b = (unsigned short*)(ws + ND);           // [ND, 1.5ND)
  unsigned short* hid   = (unsigned short*)(ws + ND + ND / 2);  // [1.5ND, 3.5ND) = NN*512 bf16
  float* outf = (float*)d_out;

  const int GX = (NN + 127) / 128;  // 782
  dim3 blk(256);

  // casts + packs
  k_cast<<<dim3(12500), blk, 0, stream>>>(x, xb, NN * DD);
  k_cast<<<dim3(16), blk, 0, stream>>>(Wq, Wqkvs, DD * DD);
  k_cast<<<dim3(16), blk, 0, stream>>>(Wk, Wqkvs + DD * DD, DD * DD);
  k_cast<<<dim3(16), blk, 0, stream>>>(Wv, Wqkvs + 2 * DD * DD, DD * DD);
  k_cast<<<dim3(16), blk, 0, stream>>>(Wsk, Wqkvs + 3 * DD * DD, DD * DD);
  k_cast<<<dim3(16), blk, 0, stream>>>(Wo, Wob, DD * DD);
  k_cast<<<dim3(64), blk, 0, stream>>>(W1, W1b, HIDD * DD);
  k_cast<<<dim3(64), blk, 0, stream>>>(W2, W2b, HIDD * DD);
  k_packb<<<dim3(1), dim3(512), 0, stream>>>(bq, bk, bv, bsk, bias512);

  // CSR build
  k_zero_cnt<<<dim3(391), blk, 0, stream>>>(cnt);
  k_count<<<dim3(1954), blk, 0, stream>>>(ei, cnt);
  k_scan1<<<dim3(391), blk, 0, stream>>>(cnt, rowptr, part);
  k_scan2<<<dim3(1), dim3(512), 0, stream>>>(part, partx);
  k_scan3<<<dim3(391), blk, 0, stream>>>(rowptr, partx, cnt);
  k_scatter<<<dim3(1954), blk, 0, stream>>>(ei, cnt, csr_src);

  // fused q|k|v|skip projection
  k_gemm_qkvs<<<dim3(GX, 4), blk, 0, stream>>>(xb, Wqkvs, bias512, qf, kvb, skipf);

  // fused attention (writes conv bf16)
  k_attn<<<dim3(12500), blk, 0, stream>>>(csr_src, rowptr, qf, kvb, skipf, alpha, convb);

  // out projection + residual(x) + LN1 -> out2 fp32 + out2b bf16
  k_gemm_ln<128, true><<<dim3(GX, 1), blk, 0, stream>>>(convb, Wob, bo, x, l1w, l1b, out2, out2b);

  // FFN1 (relu) -> hid bf16
  k_mfma_gemm<128, true><<<dim3(GX, 4), blk, 0, stream>>>(out2b, W1b, b1, hid, HIDD);

  // FFN2 + residual(out2) + LN2 -> d_out
  k_gemm_ln<512, false><<<dim3(GX, 1), blk, 0, stream>>>(hid, W2b, b2, out2, l2w, l2b, outf, nullptr);
}

// Round 6
// 387.832 us; speedup vs baseline: 8.7668x; 1.1405x over previous
//
#include <hip/hip_runtime.h>

#define NN   100000
#define NE   500000
#define DD   128
#define HH   4
#define CC   32
#define HIDD 512
#define EPSF 1e-5f

typedef __bf16 bf16x8 __attribute__((ext_vector_type(8)));
typedef float  f32x4  __attribute__((ext_vector_type(4)));

__device__ __forceinline__ unsigned short f2b(float f) {
  unsigned u = __float_as_uint(f);
  unsigned r = (u + 0x7FFFu + ((u >> 16) & 1)) >> 16;
  return (unsigned short)r;
}
__device__ __forceinline__ float b2f(unsigned short s) {
  return __uint_as_float(((unsigned)s) << 16);
}

// fp32 -> bf16 cast, 4 elems/thread (x only)
__global__ void k_cast(const float* __restrict__ src, unsigned short* __restrict__ dst, int n) {
  int i = (blockIdx.x * 256 + threadIdx.x) * 4;
  if (i >= n) return;
  float4 v = *(const float4*)&src[i];
  ushort4 o;
  o.x = f2b(v.x); o.y = f2b(v.y); o.z = f2b(v.z); o.w = f2b(v.w);
  *(ushort4*)&dst[i] = o;
}

// all weight casts + bias pack in ONE launch (209 blocks)
__global__ void k_castw(const float* __restrict__ Wq, const float* __restrict__ Wk,
                        const float* __restrict__ Wv, const float* __restrict__ Wsk,
                        const float* __restrict__ Wo, const float* __restrict__ W1,
                        const float* __restrict__ W2,
                        const float* __restrict__ bq, const float* __restrict__ bk,
                        const float* __restrict__ bv, const float* __restrict__ bs,
                        unsigned short* __restrict__ Wqkvs, unsigned short* __restrict__ Wob,
                        unsigned short* __restrict__ W1b, unsigned short* __restrict__ W2b,
                        float* __restrict__ bias512) {
  int i = blockIdx.x * 256 + threadIdx.x;
  if (i < 53248) {
    int e = i * 4;
    const float* src; unsigned short* dst; int off;
    if (e < 65536) {
      int seg = e >> 14;
      const float* s4[4] = {Wq, Wk, Wv, Wsk};
      src = s4[seg]; dst = Wqkvs + (seg << 14); off = e & 16383;
    } else if (e < 81920) { src = Wo;  dst = Wob; off = e - 65536; }
    else if (e < 147456)  { src = W1;  dst = W1b; off = e - 81920; }
    else                  { src = W2;  dst = W2b; off = e - 147456; }
    float4 v = *(const float4*)&src[off];
    ushort4 o; o.x = f2b(v.x); o.y = f2b(v.y); o.z = f2b(v.z); o.w = f2b(v.w);
    *(ushort4*)&dst[off] = o;
  } else if (i < 53376) {
    int b4 = (i - 53248) * 4;
    const float* srcs[4] = {bq, bk, bv, bs};
#pragma unroll
    for (int j = 0; j < 4; j++) {
      int idx = b4 + j;
      bias512[idx] = srcs[idx >> 7][idx & 127];
    }
  }
}

// ---------------- CSR build ----------------
__global__ void k_zero_cnt(int* __restrict__ cnt) {
  int i = blockIdx.x * 256 + threadIdx.x;
  if (i < NN) cnt[i] = 0;
}
__global__ void k_count(const int* __restrict__ ei, int* __restrict__ cnt) {
  int e = blockIdx.x * 256 + threadIdx.x;
  if (e < NE) atomicAdd(&cnt[ei[NE + e]], 1);
}
__global__ void k_scan1(const int* __restrict__ cnt, int* __restrict__ rowptr, int* __restrict__ part) {
  __shared__ int sh[256];
  int i = blockIdx.x * 256 + threadIdx.x;
  int v = (i < NN) ? cnt[i] : 0;
  sh[threadIdx.x] = v; __syncthreads();
  for (int off = 1; off < 256; off <<= 1) {
    int t = (threadIdx.x >= off) ? sh[threadIdx.x - off] : 0;
    __syncthreads();
    sh[threadIdx.x] += t;
    __syncthreads();
  }
  if (i < NN) rowptr[i] = sh[threadIdx.x] - v;  // exclusive
  if (threadIdx.x == 255) part[blockIdx.x] = sh[255];
}
__global__ void k_scan2(const int* __restrict__ part, int* __restrict__ partx) {
  __shared__ int sh[512];
  int t = threadIdx.x;
  int v = (t < 391) ? part[t] : 0;
  sh[t] = v; __syncthreads();
  for (int off = 1; off < 512; off <<= 1) {
    int u = (t >= off) ? sh[t - off] : 0;
    __syncthreads();
    sh[t] += u;
    __syncthreads();
  }
  partx[t] = sh[t] - v;
}
__global__ void k_scan3(int* __restrict__ rowptr, const int* __restrict__ partx, int* __restrict__ cnt) {
  int i = blockIdx.x * 256 + threadIdx.x;
  if (i < NN) {
    int r = rowptr[i] + partx[i >> 8];
    rowptr[i] = r;
    cnt[i] = r;
  }
  if (i == 0) rowptr[NN] = NE;
}
__global__ void k_scatter(const int* __restrict__ ei, int* __restrict__ cnt, int* __restrict__ csr_src) {
  int e = blockIdx.x * 256 + threadIdx.x;
  if (e >= NE) return;
  int d = ei[NE + e];
  int pos = atomicAdd(&cnt[d], 1);
  csr_src[pos] = ei[e];
}

// ---------------- col-loop GEMM: A[N,128] bf16, W[512,128] bf16 -> out bf16 [N,512] ----------------
// 128 rows/block; A staged once, a-frags hoisted to regs; loop 4 W col-tiles.
template <bool RELU>
__global__ __launch_bounds__(256) void k_gemm4col(const unsigned short* __restrict__ A,
                                                  const unsigned short* __restrict__ W,
                                                  const float* __restrict__ bias,
                                                  unsigned short* __restrict__ outB) {
  __shared__ unsigned short As[128 * 128];
  __shared__ unsigned short Ws[128 * 128];
  const int t = threadIdx.x;
  const int n0 = blockIdx.x * 128;
  const int w = t >> 6, l = t & 63;
  // stage A (row-swizzled 16B slots)
#pragma unroll
  for (int i = 0; i < 8; i++) {
    int chunk = t + i * 256;
    int row = chunk >> 4, c16 = chunk & 15;
    uint4 val = make_uint4(0u, 0u, 0u, 0u);
    int gr = n0 + row;
    if (gr < NN) val = *(const uint4*)(A + (size_t)gr * 128 + c16 * 8);
    *(uint4*)&As[row * 128 + ((c16 ^ (row & 7)) * 8)] = val;
  }
  __syncthreads();
  // hoist a-frags into registers (reused across all 4 col-tiles)
  bf16x8 af[4][2];
#pragma unroll
  for (int ks = 0; ks < 4; ks++) {
    const int c16 = ks * 4 + (l >> 4);
#pragma unroll
    for (int rt = 0; rt < 2; rt++) {
      int row = w * 32 + rt * 16 + (l & 15);
      af[ks][rt] = *(const bf16x8*)&As[row * 128 + ((c16 ^ (row & 7)) * 8)];
    }
  }
  for (int ct4 = 0; ct4 < 4; ++ct4) {
    __syncthreads();  // prev compute's Ws reads done
#pragma unroll
    for (int i = 0; i < 8; i++) {
      int chunk = t + i * 256;
      int row = chunk >> 4, c16 = chunk & 15;
      uint4 val = *(const uint4*)(W + (size_t)(ct4 * 128 + row) * 128 + c16 * 8);
      *(uint4*)&Ws[row * 128 + ((c16 ^ (row & 7)) * 8)] = val;
    }
    __syncthreads();
    f32x4 acc[2][8] = {};
#pragma unroll
    for (int ks = 0; ks < 4; ks++) {
      bf16x8 b[8];
      const int c16 = ks * 4 + (l >> 4);
#pragma unroll
      for (int ct = 0; ct < 8; ct++) {
        int row = ct * 16 + (l & 15);
        b[ct] = *(const bf16x8*)&Ws[row * 128 + ((c16 ^ (row & 7)) * 8)];
      }
#pragma unroll
      for (int rt = 0; rt < 2; rt++)
#pragma unroll
        for (int ct = 0; ct < 8; ct++)
          acc[rt][ct] = __builtin_amdgcn_mfma_f32_16x16x32_bf16(af[ks][rt], b[ct], acc[rt][ct], 0, 0, 0);
    }
#pragma unroll
    for (int rt = 0; rt < 2; rt++) {
      const int rbase = n0 + w * 32 + rt * 16 + ((l >> 4) * 4);
#pragma unroll
      for (int ct = 0; ct < 8; ct++) {
        const int col = ct4 * 128 + ct * 16 + (l & 15);
        const float bs = bias[col];
#pragma unroll
        for (int j = 0; j < 4; j++) {
          int r = rbase + j;
          if (r < NN) {
            float vv = acc[rt][ct][j] + bs;
            if (RELU) vv = fmaxf(vv, 0.f);
            outB[(size_t)r * 512 + col] = f2b(vv);
          }
        }
      }
    }
  }
}

// ---------------- GEMM (lda=512) + residual + LayerNorm fused epilogue ----------------
// out-proj: KTOT=128, RESF32=true (x), OUTF32=false (out2b)
// FFN2:     KTOT=512, RESF32=false (out2b), OUTF32=true (d_out)
template <int KTOT, bool RESF32, bool OUTF32>
__global__ __launch_bounds__(256) void k_gemm_ln2(const unsigned short* __restrict__ A,
                                                  const unsigned short* __restrict__ W,
                                                  const float* __restrict__ bias,
                                                  const float* __restrict__ resF,
                                                  const unsigned short* __restrict__ resB,
                                                  const float* __restrict__ lw,
                                                  const float* __restrict__ lb,
                                                  float* __restrict__ outF,
                                                  unsigned short* __restrict__ outB) {
  __shared__ unsigned short As[128 * 128];
  __shared__ unsigned short Ws[128 * 128];
  const int t = threadIdx.x;
  const int n0 = blockIdx.x * 128;
  const int w = t >> 6, l = t & 63;
  f32x4 acc[2][8] = {};
  for (int kc = 0; kc < KTOT / 128; ++kc) {
    __syncthreads();
#pragma unroll
    for (int i = 0; i < 8; i++) {
      int chunk = t + i * 256;
      int row = chunk >> 4, c16 = chunk & 15;
      uint4 val = make_uint4(0u, 0u, 0u, 0u);
      int gr = n0 + row;
      if (gr < NN) val = *(const uint4*)(A + (size_t)gr * 512 + kc * 128 + c16 * 8);
      *(uint4*)&As[row * 128 + ((c16 ^ (row & 7)) * 8)] = val;
    }
#pragma unroll
    for (int i = 0; i < 8; i++) {
      int chunk = t + i * 256;
      int row = chunk >> 4, c16 = chunk & 15;
      uint4 val = *(const uint4*)(W + (size_t)row * KTOT + kc * 128 + c16 * 8);
      *(uint4*)&Ws[row * 128 + ((c16 ^ (row & 7)) * 8)] = val;
    }
    __syncthreads();
#pragma unroll
    for (int ks = 0; ks < 4; ks++) {
      bf16x8 a[2], b[8];
      const int c16 = ks * 4 + (l >> 4);
#pragma unroll
      for (int rt = 0; rt < 2; rt++) {
        int row = w * 32 + rt * 16 + (l & 15);
        a[rt] = *(const bf16x8*)&As[row * 128 + ((c16 ^ (row & 7)) * 8)];
      }
#pragma unroll
      for (int ct = 0; ct < 8; ct++) {
        int row = ct * 16 + (l & 15);
        b[ct] = *(const bf16x8*)&Ws[row * 128 + ((c16 ^ (row & 7)) * 8)];
      }
#pragma unroll
      for (int rt = 0; rt < 2; rt++)
#pragma unroll
        for (int ct = 0; ct < 8; ct++)
          acc[rt][ct] = __builtin_amdgcn_mfma_f32_16x16x32_bf16(a[rt], b[ct], acc[rt][ct], 0, 0, 0);
    }
  }
  const int colL = l & 15;
  // bias + residual
#pragma unroll
  for (int rt = 0; rt < 2; rt++) {
    const int lrow0 = n0 + w * 32 + rt * 16 + ((l >> 4) * 4);
#pragma unroll
    for (int ct = 0; ct < 8; ct++) {
      const int col = ct * 16 + colL;
      const float bs = bias[col];
#pragma unroll
      for (int j = 0; j < 4; j++) {
        int grow = lrow0 + j;
        float rv = 0.f;
        if (grow < NN)
          rv = RESF32 ? resF[(size_t)grow * DD + col] : b2f(resB[(size_t)grow * DD + col]);
        acc[rt][ct][j] += bs + rv;
      }
    }
  }
  // per-row LayerNorm (row's 128 cols live in 16 lanes x 8 ct-regs)
#pragma unroll
  for (int rt = 0; rt < 2; rt++) {
    const int lrow0 = n0 + w * 32 + rt * 16 + ((l >> 4) * 4);
#pragma unroll
    for (int j = 0; j < 4; j++) {
      float s = 0.f;
#pragma unroll
      for (int ct = 0; ct < 8; ct++) s += acc[rt][ct][j];
      s += __shfl_xor(s, 1, 64); s += __shfl_xor(s, 2, 64);
      s += __shfl_xor(s, 4, 64); s += __shfl_xor(s, 8, 64);
      const float mu = s * (1.f / 128.f);
      float vs = 0.f;
#pragma unroll
      for (int ct = 0; ct < 8; ct++) { float d = acc[rt][ct][j] - mu; vs += d * d; }
      vs += __shfl_xor(vs, 1, 64); vs += __shfl_xor(vs, 2, 64);
      vs += __shfl_xor(vs, 4, 64); vs += __shfl_xor(vs, 8, 64);
      const float rs = rsqrtf(vs * (1.f / 128.f) + EPSF);
      const int grow = lrow0 + j;
      if (grow < NN) {
#pragma unroll
        for (int ct = 0; ct < 8; ct++) {
          const int col = ct * 16 + colL;
          float yv = (acc[rt][ct][j] - mu) * rs * lw[col] + lb[col];
          if (OUTF32) outF[(size_t)grow * DD + col] = yv;
          else        outB[(size_t)grow * DD + col] = f2b(yv);
        }
      }
    }
  }
}

// ---------------- fused attention, all-bf16 node features [N,512] ----------------
// q 0:128, k 128:256, v 256:384, skip 384:512; conv written in-place into skip slot.
__global__ __launch_bounds__(256) void k_attn(const int* __restrict__ csr_src,
                                              const int* __restrict__ rowptr,
                                              unsigned short* qkvsb,
                                              float* __restrict__ alpha) {
  const int l = threadIdx.x & 31;
  const int node = blockIdx.x * 8 + (threadIdx.x >> 5);  // grid exact: 12500*8
  const int row0 = rowptr[node], row1 = rowptr[node + 1];
  const int h8 = l >> 3;
  ushort4 qu = *(const ushort4*)&qkvsb[(size_t)node * 512 + l * 4];
  const float qx = b2f(qu.x), qy = b2f(qu.y), qz = b2f(qu.z), qw = b2f(qu.w);
  float mmax = -3.4e38f;
  // pass 1: logits + running max
  for (int p = row0; p < row1; ++p) {
    int s = csr_src[p];
    ushort4 kr = *(const ushort4*)&qkvsb[(size_t)s * 512 + 128 + l * 4];
    float d = qx * b2f(kr.x) + qy * b2f(kr.y) + qz * b2f(kr.z) + qw * b2f(kr.w);
    d += __shfl_xor(d, 1, 32);
    d += __shfl_xor(d, 2, 32);
    d += __shfl_xor(d, 4, 32);
    d *= 0.17677669529663687f;
    mmax = fmaxf(mmax, d);
    if ((l & 7) == 0) alpha[(size_t)p * 4 + h8] = d;
  }
  // pass 2: exp + z
  const int myh = l & 3;
  const float mh = __shfl(mmax, myh * 8, 32);
  float zacc = 0.f;
  for (int pb = row0; pb < row1; pb += 8) {
    int idx = pb + (l >> 2);
    float e = 0.f;
    if (idx < row1) {
      float a = alpha[(size_t)idx * 4 + myh];
      e = __expf(a - mh);
      alpha[(size_t)idx * 4 + myh] = e;
    }
    zacc += e;
  }
  zacc += __shfl_xor(zacc, 4, 32);
  zacc += __shfl_xor(zacc, 8, 32);
  zacc += __shfl_xor(zacc, 16, 32);
  const float rzh = 1.f / __shfl(zacc, h8, 4);
  // pass 3: conv = skip + sum a*v -> write back into skip slot (bf16)
  ushort4 su = *(const ushort4*)&qkvsb[(size_t)node * 512 + 384 + l * 4];
  float ax = b2f(su.x), ay = b2f(su.y), az = b2f(su.z), aw = b2f(su.w);
  for (int p = row0; p < row1; ++p) {
    int s = csr_src[p];
    float wgt = alpha[(size_t)p * 4 + h8] * rzh;
    ushort4 vr = *(const ushort4*)&qkvsb[(size_t)s * 512 + 256 + l * 4];
    ax += wgt * b2f(vr.x); ay += wgt * b2f(vr.y);
    az += wgt * b2f(vr.z); aw += wgt * b2f(vr.w);
  }
  ushort4 o;
  o.x = f2b(ax); o.y = f2b(ay); o.z = f2b(az); o.w = f2b(aw);
  *(ushort4*)&qkvsb[(size_t)node * 512 + 384 + l * 4] = o;
}

extern "C" void kernel_launch(void* const* d_in, const int* in_sizes, int n_in,
                              void* d_out, int out_size, void* d_ws, size_t ws_size,
                              hipStream_t stream) {
  const float* x   = (const float*)d_in[0];
  const int*   ei  = (const int*)d_in[1];
  const float* Wq  = (const float*)d_in[2];
  const float* bq  = (const float*)d_in[3];
  const float* Wk  = (const float*)d_in[4];
  const float* bk  = (const float*)d_in[5];
  const float* Wv  = (const float*)d_in[6];
  const float* bv  = (const float*)d_in[7];
  const float* Wsk = (const float*)d_in[8];
  const float* bsk = (const float*)d_in[9];
  const float* Wo  = (const float*)d_in[10];
  const float* bo  = (const float*)d_in[11];
  const float* l1w = (const float*)d_in[12];
  const float* l1b = (const float*)d_in[13];
  const float* l2w = (const float*)d_in[14];
  const float* l2b = (const float*)d_in[15];
  const float* W1  = (const float*)d_in[16];
  const float* b1  = (const float*)d_in[17];
  const float* W2  = (const float*)d_in[18];
  const float* b2  = (const float*)d_in[19];

  // ---- workspace layout (~140 MB peak) ----
  unsigned short* wsu = (unsigned short*)d_ws;
  unsigned short* qkvsb = wsu;                          // [N,512] bf16, 102.4MB (later: hid)
  unsigned short* xb    = wsu + (size_t)NN * 512;       // [N,128] bf16, 25.6MB (later: out2b)
  float* alpha = (float*)(xb + (size_t)NN * DD);        // [E,4] fp32, 8MB
  int* csr_src = (int*)(alpha + (size_t)NE * HH);       // 2MB
  int* rowptr  = csr_src + NE;                          // N+1
  int* cnt     = rowptr + NN + 1;                       // N
  int* part    = cnt + NN;                              // 391
  int* partx   = part + 512;                            // 512
  unsigned short* Wqkvs = (unsigned short*)(partx + 512);  // [512,128] bf16
  unsigned short* Wob   = Wqkvs + 512 * DD;
  unsigned short* W1b   = Wob + DD * DD;
  unsigned short* W2b   = W1b + (size_t)HIDD * DD;
  float* bias512        = (float*)(W2b + (size_t)HIDD * DD);

  unsigned short* out2b = xb;        // xb dead after qkvs GEMM
  unsigned short* hid   = qkvsb;     // qkvsb dead after out-proj
  float* outf = (float*)d_out;

  const int GX = (NN + 127) / 128;  // 782
  dim3 blk(256);

  // casts (x) + all weights/biases in one launch
  k_cast<<<dim3(12500), blk, 0, stream>>>(x, xb, NN * DD);
  k_castw<<<dim3(209), blk, 0, stream>>>(Wq, Wk, Wv, Wsk, Wo, W1, W2, bq, bk, bv, bsk,
                                         Wqkvs, Wob, W1b, W2b, bias512);

  // CSR build
  k_zero_cnt<<<dim3(391), blk, 0, stream>>>(cnt);
  k_count<<<dim3(1954), blk, 0, stream>>>(ei, cnt);
  k_scan1<<<dim3(391), blk, 0, stream>>>(cnt, rowptr, part);
  k_scan2<<<dim3(1), dim3(512), 0, stream>>>(part, partx);
  k_scan3<<<dim3(391), blk, 0, stream>>>(rowptr, partx, cnt);
  k_scatter<<<dim3(1954), blk, 0, stream>>>(ei, cnt, csr_src);

  // fused q|k|v|skip projection -> qkvsb bf16 [N,512]
  k_gemm4col<false><<<dim3(GX), blk, 0, stream>>>(xb, Wqkvs, bias512, qkvsb);

  // fused attention (conv lands in skip slot, bf16)
  k_attn<<<dim3(12500), blk, 0, stream>>>(csr_src, rowptr, qkvsb, alpha);

  // out projection (A = conv slot, lda=512) + residual(x fp32) + LN1 -> out2b bf16
  k_gemm_ln2<128, true, false><<<dim3(GX), blk, 0, stream>>>(
      qkvsb + 384, Wob, bo, x, nullptr, l1w, l1b, nullptr, out2b);

  // FFN1 (relu) -> hid bf16 [N,512]   (reads out2b lda=128... uses k_gemm4col: lda=128 OK)
  k_gemm4col<true><<<dim3(GX), blk, 0, stream>>>(out2b, W1b, b1, hid);

  // FFN2 (K=512) + residual(out2b bf16) + LN2 -> d_out fp32
  k_gemm_ln2<512, false, true><<<dim3(GX), blk, 0, stream>>>(
      hid, W2b, b2, nullptr, out2b, l2w, l2b, outf, nullptr);
}

// Round 7
// 366.540 us; speedup vs baseline: 9.2760x; 1.0581x over previous
//
#include <hip/hip_runtime.h>

#define NN   100000
#define NE   500000
#define DD   128
#define HH   4
#define HIDD 512
#define EPSF 1e-5f

typedef __bf16 bf16x8 __attribute__((ext_vector_type(8)));
typedef float  f32x4  __attribute__((ext_vector_type(4)));

__device__ __forceinline__ unsigned short f2b(float f) {
  unsigned u = __float_as_uint(f);
  unsigned r = (u + 0x7FFFu + ((u >> 16) & 1)) >> 16;
  return (unsigned short)r;
}
__device__ __forceinline__ float b2f(unsigned short s) {
  return __uint_as_float(((unsigned)s) << 16);
}

// async global->LDS, 16B per lane; LDS dest must be wave-uniform base (+lane*16 by HW)
#define GLOAD16(ldsp, gp) __builtin_amdgcn_global_load_lds(                      \
    (const __attribute__((address_space(1))) void*)(gp),                         \
    (__attribute__((address_space(3))) void*)(ldsp), 16, 0, 0)

// stage a 128x128 bf16 tile: linear LDS dest, inverse-swizzled global source.
// read side uses slot (c16 ^ (row&7)) exactly as the register-staged layout.
__device__ __forceinline__ void stage16_async(unsigned short* lds,
                                              const unsigned short* g,
                                              int ldg, int t) {
  const int w = t >> 6, l = t & 63;
#pragma unroll
  for (int i = 0; i < 8; i++) {
    const int chunk0 = i * 256 + w * 64;   // wave-uniform
    const int chunk = chunk0 + l;
    const int row = chunk >> 4, c16 = chunk & 15;
    const int gslot = c16 ^ (row & 7);
    GLOAD16(lds + (size_t)chunk0 * 8, g + (size_t)row * ldg + gslot * 8);
  }
}

// all weight casts + bias pack in ONE launch (209 blocks)
__global__ void k_castw(const float* __restrict__ Wq, const float* __restrict__ Wk,
                        const float* __restrict__ Wv, const float* __restrict__ Wsk,
                        const float* __restrict__ Wo, const float* __restrict__ W1,
                        const float* __restrict__ W2,
                        const float* __restrict__ bq, const float* __restrict__ bk,
                        const float* __restrict__ bv, const float* __restrict__ bs,
                        unsigned short* __restrict__ Wqkvs, unsigned short* __restrict__ Wob,
                        unsigned short* __restrict__ W1b, unsigned short* __restrict__ W2b,
                        float* __restrict__ bias512) {
  int i = blockIdx.x * 256 + threadIdx.x;
  if (i < 53248) {
    int e = i * 4;
    const float* src; unsigned short* dst; int off;
    if (e < 65536) {
      int seg = e >> 14;
      const float* s4[4] = {Wq, Wk, Wv, Wsk};
      src = s4[seg]; dst = Wqkvs + (seg << 14); off = e & 16383;
    } else if (e < 81920) { src = Wo;  dst = Wob; off = e - 65536; }
    else if (e < 147456)  { src = W1;  dst = W1b; off = e - 81920; }
    else                  { src = W2;  dst = W2b; off = e - 147456; }
    float4 v = *(const float4*)&src[off];
    ushort4 o; o.x = f2b(v.x); o.y = f2b(v.y); o.z = f2b(v.z); o.w = f2b(v.w);
    *(ushort4*)&dst[off] = o;
  } else if (i < 53376) {
    int b4 = (i - 53248) * 4;
    const float* srcs[4] = {bq, bk, bv, bs};
#pragma unroll
    for (int j = 0; j < 4; j++) {
      int idx = b4 + j;
      bias512[idx] = srcs[idx >> 7][idx & 127];
    }
  }
}

// ---------------- CSR build ----------------
__global__ void k_zero_cnt(int* __restrict__ cnt) {
  int i = blockIdx.x * 256 + threadIdx.x;
  if (i < NN) cnt[i] = 0;
}
__global__ void k_count(const int* __restrict__ ei, int* __restrict__ cnt) {
  int e = blockIdx.x * 256 + threadIdx.x;
  if (e < NE) atomicAdd(&cnt[ei[NE + e]], 1);
}
__global__ void k_scan1(const int* __restrict__ cnt, int* __restrict__ rowptr, int* __restrict__ part) {
  __shared__ int sh[256];
  int i = blockIdx.x * 256 + threadIdx.x;
  int v = (i < NN) ? cnt[i] : 0;
  sh[threadIdx.x] = v; __syncthreads();
  for (int off = 1; off < 256; off <<= 1) {
    int t = (threadIdx.x >= off) ? sh[threadIdx.x - off] : 0;
    __syncthreads();
    sh[threadIdx.x] += t;
    __syncthreads();
  }
  if (i < NN) rowptr[i] = sh[threadIdx.x] - v;  // exclusive
  if (threadIdx.x == 255) part[blockIdx.x] = sh[255];
}
__global__ void k_scan2(const int* __restrict__ part, int* __restrict__ partx) {
  __shared__ int sh[512];
  int t = threadIdx.x;
  int v = (t < 391) ? part[t] : 0;
  sh[t] = v; __syncthreads();
  for (int off = 1; off < 512; off <<= 1) {
    int u = (t >= off) ? sh[t - off] : 0;
    __syncthreads();
    sh[t] += u;
    __syncthreads();
  }
  partx[t] = sh[t] - v;
}
__global__ void k_scan3(int* __restrict__ rowptr, const int* __restrict__ partx, int* __restrict__ cnt) {
  int i = blockIdx.x * 256 + threadIdx.x;
  if (i < NN) {
    int r = rowptr[i] + partx[i >> 8];
    rowptr[i] = r;
    cnt[i] = r;
  }
  if (i == 0) rowptr[NN] = NE;
}
__global__ void k_scatter(const int* __restrict__ ei, int* __restrict__ cnt, int* __restrict__ csr_src) {
  int e = blockIdx.x * 256 + threadIdx.x;
  if (e >= NE) return;
  int d = ei[NE + e];
  int pos = atomicAdd(&cnt[d], 1);
  csr_src[pos] = ei[e];
}

// ---------------- col-loop GEMM: A[N,128] -> out bf16 [N,512] (4 W col-tiles) ----------------
// F32A: A is fp32 (x), staged via registers with cast; else bf16 via global_load_lds.
template <bool F32A, bool RELU>
__global__ __launch_bounds__(256) void k_gemm4(const void* __restrict__ Av,
                                               const unsigned short* __restrict__ W,
                                               const float* __restrict__ bias,
                                               unsigned short* __restrict__ outB) {
  __shared__ __align__(16) unsigned short As[128 * 128];
  __shared__ __align__(16) unsigned short Ws[128 * 128];
  const int t = threadIdx.x;
  const int n0 = blockIdx.x * 128;
  const int w = t >> 6, l = t & 63;
  // stage A once
  if constexpr (F32A) {
    const float* A = (const float*)Av;
#pragma unroll
    for (int i = 0; i < 8; i++) {
      int chunk = t + i * 256;
      int row = chunk >> 4, c16 = chunk & 15;
      int gr = n0 + row;
      ushort4 u0 = make_ushort4(0, 0, 0, 0), u1 = make_ushort4(0, 0, 0, 0);
      if (gr < NN) {
        float4 f0 = *(const float4*)(A + (size_t)gr * 128 + c16 * 8);
        float4 f1 = *(const float4*)(A + (size_t)gr * 128 + c16 * 8 + 4);
        u0.x = f2b(f0.x); u0.y = f2b(f0.y); u0.z = f2b(f0.z); u0.w = f2b(f0.w);
        u1.x = f2b(f1.x); u1.y = f2b(f1.y); u1.z = f2b(f1.z); u1.w = f2b(f1.w);
      }
      unsigned short* dst = &As[row * 128 + ((c16 ^ (row & 7)) * 8)];
      *(ushort4*)dst = u0;
      *(ushort4*)(dst + 4) = u1;
    }
  } else {
    stage16_async(As, (const unsigned short*)Av + (size_t)n0 * 128, 128, t);
  }
  __syncthreads();
  // hoist a-frags (reused across all 4 col-tiles)
  bf16x8 af[4][2];
#pragma unroll
  for (int ks = 0; ks < 4; ks++) {
    const int c16 = ks * 4 + (l >> 4);
#pragma unroll
    for (int rt = 0; rt < 2; rt++) {
      int row = w * 32 + rt * 16 + (l & 15);
      af[ks][rt] = *(const bf16x8*)&As[row * 128 + ((c16 ^ (row & 7)) * 8)];
    }
  }
  for (int ct4 = 0; ct4 < 4; ++ct4) {
    __syncthreads();  // prior Ws readers done
    stage16_async(Ws, W + (size_t)ct4 * 128 * 128, 128, t);
    __syncthreads();
    f32x4 acc[2][8] = {};
#pragma unroll
    for (int ks = 0; ks < 4; ks++) {
      bf16x8 b[8];
      const int c16 = ks * 4 + (l >> 4);
#pragma unroll
      for (int ct = 0; ct < 8; ct++) {
        int row = ct * 16 + (l & 15);
        b[ct] = *(const bf16x8*)&Ws[row * 128 + ((c16 ^ (row & 7)) * 8)];
      }
#pragma unroll
      for (int rt = 0; rt < 2; rt++)
#pragma unroll
        for (int ct = 0; ct < 8; ct++)
          acc[rt][ct] = __builtin_amdgcn_mfma_f32_16x16x32_bf16(af[ks][rt], b[ct], acc[rt][ct], 0, 0, 0);
    }
#pragma unroll
    for (int rt = 0; rt < 2; rt++) {
      const int rbase = n0 + w * 32 + rt * 16 + ((l >> 4) * 4);
#pragma unroll
      for (int ct = 0; ct < 8; ct++) {
        const int col = ct4 * 128 + ct * 16 + (l & 15);
        const float bs = bias[col];
#pragma unroll
        for (int j = 0; j < 4; j++) {
          int r = rbase + j;
          if (r < NN) {
            float vv = acc[rt][ct][j] + bs;
            if (RELU) vv = fmaxf(vv, 0.f);
            outB[(size_t)r * 512 + col] = f2b(vv);
          }
        }
      }
    }
  }
}

// ---------------- GEMM (A lda=512 bf16) + residual + LayerNorm ----------------
template <int KTOT, bool RESF32, bool OUTF32>
__global__ __launch_bounds__(256) void k_gemm_ln2(const unsigned short* __restrict__ A,
                                                  const unsigned short* __restrict__ W,
                                                  const float* __restrict__ bias,
                                                  const float* __restrict__ resF,
                                                  const unsigned short* __restrict__ resB,
                                                  const float* __restrict__ lw,
                                                  const float* __restrict__ lb,
                                                  float* __restrict__ outF,
                                                  unsigned short* __restrict__ outB) {
  __shared__ __align__(16) unsigned short As[128 * 128];
  __shared__ __align__(16) unsigned short Ws[128 * 128];
  const int t = threadIdx.x;
  const int n0 = blockIdx.x * 128;
  const int w = t >> 6, l = t & 63;
  f32x4 acc[2][8] = {};
  for (int kc = 0; kc < KTOT / 128; ++kc) {
    __syncthreads();
    stage16_async(As, A + (size_t)n0 * 512 + kc * 128, 512, t);
    stage16_async(Ws, W + kc * 128, KTOT, t);
    __syncthreads();
#pragma unroll
    for (int ks = 0; ks < 4; ks++) {
      bf16x8 a[2], b[8];
      const int c16 = ks * 4 + (l >> 4);
#pragma unroll
      for (int rt = 0; rt < 2; rt++) {
        int row = w * 32 + rt * 16 + (l & 15);
        a[rt] = *(const bf16x8*)&As[row * 128 + ((c16 ^ (row & 7)) * 8)];
      }
#pragma unroll
      for (int ct = 0; ct < 8; ct++) {
        int row = ct * 16 + (l & 15);
        b[ct] = *(const bf16x8*)&Ws[row * 128 + ((c16 ^ (row & 7)) * 8)];
      }
#pragma unroll
      for (int rt = 0; rt < 2; rt++)
#pragma unroll
        for (int ct = 0; ct < 8; ct++)
          acc[rt][ct] = __builtin_amdgcn_mfma_f32_16x16x32_bf16(a[rt], b[ct], acc[rt][ct], 0, 0, 0);
    }
  }
  const int colL = l & 15;
  // bias + residual
#pragma unroll
  for (int rt = 0; rt < 2; rt++) {
    const int lrow0 = n0 + w * 32 + rt * 16 + ((l >> 4) * 4);
#pragma unroll
    for (int ct = 0; ct < 8; ct++) {
      const int col = ct * 16 + colL;
      const float bs = bias[col];
#pragma unroll
      for (int j = 0; j < 4; j++) {
        int grow = lrow0 + j;
        float rv = 0.f;
        if (grow < NN)
          rv = RESF32 ? resF[(size_t)grow * DD + col] : b2f(resB[(size_t)grow * DD + col]);
        acc[rt][ct][j] += bs + rv;
      }
    }
  }
  // per-row LayerNorm (row's 128 cols live in 16 lanes x 8 ct-regs)
#pragma unroll
  for (int rt = 0; rt < 2; rt++) {
    const int lrow0 = n0 + w * 32 + rt * 16 + ((l >> 4) * 4);
#pragma unroll
    for (int j = 0; j < 4; j++) {
      float s = 0.f;
#pragma unroll
      for (int ct = 0; ct < 8; ct++) s += acc[rt][ct][j];
      s += __shfl_xor(s, 1, 64); s += __shfl_xor(s, 2, 64);
      s += __shfl_xor(s, 4, 64); s += __shfl_xor(s, 8, 64);
      const float mu = s * (1.f / 128.f);
      float vs = 0.f;
#pragma unroll
      for (int ct = 0; ct < 8; ct++) { float d = acc[rt][ct][j] - mu; vs += d * d; }
      vs += __shfl_xor(vs, 1, 64); vs += __shfl_xor(vs, 2, 64);
      vs += __shfl_xor(vs, 4, 64); vs += __shfl_xor(vs, 8, 64);
      const float rs = rsqrtf(vs * (1.f / 128.f) + EPSF);
      const int grow = lrow0 + j;
      if (grow < NN) {
#pragma unroll
        for (int ct = 0; ct < 8; ct++) {
          const int col = ct * 16 + colL;
          float yv = (acc[rt][ct][j] - mu) * rs * lw[col] + lb[col];
          if (OUTF32) outF[(size_t)grow * DD + col] = yv;
          else        outB[(size_t)grow * DD + col] = f2b(yv);
        }
      }
    }
  }
}

// ---------------- single-pass fused attention ----------------
// qkvsb [N,512] bf16: q 0:128, k 128:256, v 256:384, skip 384:512 (conv written in-place).
// Softmax without max-subtraction (mathematically identical; logits are O(10)).
__global__ __launch_bounds__(256) void k_attn(const int* __restrict__ csr_src,
                                              const int* __restrict__ rowptr,
                                              unsigned short* qkvsb) {
  const int l = threadIdx.x & 31;
  const int node = blockIdx.x * 8 + (threadIdx.x >> 5);  // grid exact: 12500*8
  const int row0 = rowptr[node], row1 = rowptr[node + 1];
  ushort4 qu = *(const ushort4*)&qkvsb[(size_t)node * 512 + l * 4];
  const float qx = b2f(qu.x), qy = b2f(qu.y), qz = b2f(qu.z), qw = b2f(qu.w);
  float ax = 0.f, ay = 0.f, az = 0.f, aw = 0.f, z = 0.f;
  for (int p = row0; p < row1; ++p) {
    int s = csr_src[p];
    const unsigned short* base = &qkvsb[(size_t)s * 512];
    ushort4 kr = *(const ushort4*)(base + 128 + l * 4);  // k row
    ushort4 vr = *(const ushort4*)(base + 256 + l * 4);  // v row (same cache neighborhood)
    float d = qx * b2f(kr.x) + qy * b2f(kr.y) + qz * b2f(kr.z) + qw * b2f(kr.w);
    d += __shfl_xor(d, 1, 32);
    d += __shfl_xor(d, 2, 32);
    d += __shfl_xor(d, 4, 32);
    float e = __expf(d * 0.17677669529663687f);  // 1/sqrt(32)
    z += e;
    ax += e * b2f(vr.x); ay += e * b2f(vr.y);
    az += e * b2f(vr.z); aw += e * b2f(vr.w);
  }
  const float rz = (z > 0.f) ? (1.f / z) : 0.f;  // guard in-degree-0 nodes
  ushort4 su = *(const ushort4*)&qkvsb[(size_t)node * 512 + 384 + l * 4];
  ushort4 o;
  o.x = f2b(b2f(su.x) + ax * rz);
  o.y = f2b(b2f(su.y) + ay * rz);
  o.z = f2b(b2f(su.z) + az * rz);
  o.w = f2b(b2f(su.w) + aw * rz);
  *(ushort4*)&qkvsb[(size_t)node * 512 + 384 + l * 4] = o;
}

extern "C" void kernel_launch(void* const* d_in, const int* in_sizes, int n_in,
                              void* d_out, int out_size, void* d_ws, size_t ws_size,
                              hipStream_t stream) {
  const float* x   = (const float*)d_in[0];
  const int*   ei  = (const int*)d_in[1];
  const float* Wq  = (const float*)d_in[2];
  const float* bq  = (const float*)d_in[3];
  const float* Wk  = (const float*)d_in[4];
  const float* bk  = (const float*)d_in[5];
  const float* Wv  = (const float*)d_in[6];
  const float* bv  = (const float*)d_in[7];
  const float* Wsk = (const float*)d_in[8];
  const float* bsk = (const float*)d_in[9];
  const float* Wo  = (const float*)d_in[10];
  const float* bo  = (const float*)d_in[11];
  const float* l1w = (const float*)d_in[12];
  const float* l1b = (const float*)d_in[13];
  const float* l2w = (const float*)d_in[14];
  const float* l2b = (const float*)d_in[15];
  const float* W1  = (const float*)d_in[16];
  const float* b1  = (const float*)d_in[17];
  const float* W2  = (const float*)d_in[18];
  const float* b2  = (const float*)d_in[19];

  // ---- workspace layout (~132 MB peak) ----
  unsigned short* wsu = (unsigned short*)d_ws;
  unsigned short* qkvsb = wsu;                           // [N,512] bf16 (later: hid)
  unsigned short* out2b = wsu + (size_t)NN * 512;        // [N,128] bf16
  int* csr_src = (int*)(out2b + (size_t)NN * DD);        // NE
  int* rowptr  = csr_src + NE;                           // N+1
  int* cnt     = rowptr + NN + 1;                        // N
  int* part    = cnt + NN;                               // 391
  int* partx   = part + 512;                             // 512
  // 16B-align the weight region (global_load_lds needs 16B-aligned global srcs)
  size_t woff = (size_t)((partx + 512) - (int*)d_ws);
  woff = (woff + 3) & ~(size_t)3;
  unsigned short* Wqkvs = (unsigned short*)((int*)d_ws + woff);  // [512,128]
  unsigned short* Wob   = Wqkvs + 512 * DD;                      // [128,128]
  unsigned short* W1b   = Wob + DD * DD;                         // [512,128]
  unsigned short* W2b   = W1b + (size_t)HIDD * DD;               // [128,512]
  float* bias512        = (float*)(W2b + (size_t)DD * HIDD);

  unsigned short* hid = qkvsb;  // qkvsb dead after out-proj
  float* outf = (float*)d_out;

  const int GX = (NN + 127) / 128;  // 782
  dim3 blk(256);

  // weights/biases cast+pack (one launch)
  k_castw<<<dim3(209), blk, 0, stream>>>(Wq, Wk, Wv, Wsk, Wo, W1, W2, bq, bk, bv, bsk,
                                         Wqkvs, Wob, W1b, W2b, bias512);

  // CSR build
  k_zero_cnt<<<dim3(391), blk, 0, stream>>>(cnt);
  k_count<<<dim3(1954), blk, 0, stream>>>(ei, cnt);
  k_scan1<<<dim3(391), blk, 0, stream>>>(cnt, rowptr, part);
  k_scan2<<<dim3(1), dim3(512), 0, stream>>>(part, partx);
  k_scan3<<<dim3(391), blk, 0, stream>>>(rowptr, partx, cnt);
  k_scatter<<<dim3(1954), blk, 0, stream>>>(ei, cnt, csr_src);

  // fused q|k|v|skip projection: x fp32 -> qkvsb bf16 [N,512] (cast fused into staging)
  k_gemm4<true, false><<<dim3(GX), blk, 0, stream>>>(x, Wqkvs, bias512, qkvsb);

  // single-pass attention (conv lands in skip slot)
  k_attn<<<dim3(12500), blk, 0, stream>>>(csr_src, rowptr, qkvsb);

  // out projection (A = conv slot) + residual(x fp32) + LN1 -> out2b bf16
  k_gemm_ln2<128, true, false><<<dim3(GX), blk, 0, stream>>>(
      qkvsb + 384, Wob, bo, x, nullptr, l1w, l1b, nullptr, out2b);

  // FFN1 (relu) -> hid bf16 [N,512]
  k_gemm4<false, true><<<dim3(GX), blk, 0, stream>>>(out2b, W1b, b1, hid);

  // FFN2 (K=512) + residual(out2b bf16) + LN2 -> d_out fp32
  k_gemm_ln2<512, false, true><<<dim3(GX), blk, 0, stream>>>(
      hid, W2b, b2, nullptr, out2b, l2w, l2b, outf, nullptr);
}